// Round 9
// baseline (812.326 us; speedup 1.0000x reference)
//
#include <hip/hip_runtime.h>
#include <hip/hip_fp8.h>

typedef __bf16 bf16_t;
typedef __bf16 bf16x8 __attribute__((ext_vector_type(8)));
typedef float floatx16 __attribute__((ext_vector_type(16)));
typedef unsigned long long u64;

#define B_ 16
#define N_ 4096
#define K_ 32

// ws layout (bytes):
//   idx   u16 [16][4096][32]         @ 0        (4194304)
//   g_enc u32 [16][1024]             @ 4194304  (65536)
//   w3f8  fp8 frag-major [131072]    @ 4259840  (131072)   (= w3 * 16)
//   w2sw  bf16 frag-major [8192]     @ 4390912  (16384)
//   tmat  f32 [16][9]                @ 4407296  (576)

__device__ __forceinline__ unsigned enc_f(float f) {
    unsigned u = __float_as_uint(f);
    return (u & 0x80000000u) ? ~u : (u | 0x80000000u);
}
__device__ __forceinline__ float dec_f(unsigned e) {
    return __uint_as_float((e & 0x80000000u) ? (e & 0x7fffffffu) : ~e);
}

// ---------------------------------------------------------------------------
// K1: kNN top-32 (unchanged core). 8 threads/query, register top-12,
// med3-chain insert, 8-way LDS tournament merge. grid 1024 x 512.
// Side jobs: zero g_enc, build fp8 frag-major w3f8 (x16) + bf16 w2sw.
// w3f8 layout: byte o -> jj=o&7, l=(o>>3)&63, ks=(o>>9)&7, cb=o>>12;
// value = fp8(16 * w3[cb*32+(l&31)][ks*16+(l>>5)*8+jj])  — each (cb,ks)
// fragment is 512 contiguous bytes (one coalesced dwordx2 per wave).
// ---------------------------------------------------------------------------
__global__ __launch_bounds__(512, 4) void knn_kernel(
    const float* __restrict__ x, const float* __restrict__ w3,
    const float* __restrict__ w2, unsigned short* __restrict__ idxb,
    unsigned* __restrict__ g_enc, unsigned char* __restrict__ w3f8,
    bf16_t* __restrict__ w2sw)
{
    __shared__ __align__(16) float4 cand[8 * 513];   // 65664 B
    unsigned* lists = (unsigned*)cand;               // reused after scan
    const int tid = threadIdx.x;
    const int bid = blockIdx.x;  // 1024 blocks

    {
        const int g = bid * 512 + tid;
        if (g < 131072) {
            const int jj = g & 7, lI = (g >> 3) & 63, ks = (g >> 9) & 7, cb = g >> 12;
            const int lmI = lI & 31, hiI = lI >> 5;
            __hip_fp8_e4m3 t(16.0f * w3[(cb * 32 + lmI) * 128 + ks * 16 + hiI * 8 + jj]);
            w3f8[g] = t.__x;
        } else if (g < 139264) {
            const int o = g - 131072;
            const int f = o >> 9, r = o & 511, lI = r >> 3, jj = r & 7;
            const int ks = f & 3, nb = f >> 2, lmI = lI & 31, hiI = lI >> 5;
            w2sw[o] = (bf16_t)w2[(nb * 32 + lmI) * 64 + ks * 16 + hiI * 8 + jj];
        } else if (g < 155648) {
            g_enc[g - 139264] = 0u;
        }
    }

    const int b  = bid >> 6;                    // 64 blocks per batch
    const int q  = tid >> 3;                    // local query 0..63
    const int n  = (bid & 63) * 64 + q;         // global query index
    const int t  = tid & 7;                     // candidate chunk
    const float* xb = x + b * 3 * N_;

    for (int j = tid; j < N_; j += 512) {
        float cx = xb[j], cy = xb[N_ + j], cz = xb[2 * N_ + j];
        cand[j + (j >> 9)] = make_float4(-2.f * cx, -2.f * cy, -2.f * cz,
                                         fmaf(cx, cx, fmaf(cy, cy, cz * cz)));
    }
    __syncthreads();

    const float xi0 = xb[n], xi1 = xb[N_ + n], xi2 = xb[2 * N_ + n];
    const float xisq = fmaf(xi0, xi0, fmaf(xi1, xi1, xi2 * xi2));

    unsigned r[12];
    #pragma unroll
    for (int s = 0; s < 12; s++) r[s] = 0x7F7FFFFFu;   // FLT_MAX sentinel

    const int j0 = t * 512;
    const int pb = t * 513;
    #pragma unroll 8
    for (int jj = 0; jj < 512; jj++) {
        const float4 c = cand[pb + jj];
        const float d = fmaf(c.z, xi2, fmaf(c.y, xi1, fmaf(c.x, xi0, c.w)));
        const float df = fmaxf(d + xisq, 0.f);
        const unsigned key = (__float_as_uint(df) & 0xFFFFF000u) | (unsigned)(j0 + jj);
        #pragma unroll
        for (int s = 11; s >= 1; s--) {
            const unsigned hv = r[s - 1] > key ? r[s - 1] : key;
            r[s] = r[s] < hv ? r[s] : hv;           // med3
        }
        r[0] = r[0] < key ? r[0] : key;
    }
    __syncthreads();   // cand reads done; reuse LDS for lists

    #pragma unroll
    for (int k = 0; k < 12; k++) lists[tid * 13 + k] = r[k];   // stride 13: conflict-free
    __syncthreads();

    if (tid < 64) {
        #define LRD(i, p) lists[(tid * 8 + (i)) * 13 + (p)]
        unsigned h0 = LRD(0, 0), h1 = LRD(1, 0), h2 = LRD(2, 0), h3 = LRD(3, 0);
        unsigned h4 = LRD(4, 0), h5 = LRD(5, 0), h6 = LRD(6, 0), h7 = LRD(7, 0);
        int p0 = 0, p1 = 0, p2 = 0, p3 = 0, p4 = 0, p5 = 0, p6 = 0, p7 = 0;
        const int nq = (bid & 63) * 64 + tid;
        unsigned short* op = idxb + ((size_t)(b * N_ + nq)) * K_;
        #pragma unroll 1
        for (int k = 0; k < K_; k++) {
            unsigned m01 = h0 < h1 ? h0 : h1, m23 = h2 < h3 ? h2 : h3;
            unsigned m45 = h4 < h5 ? h4 : h5, m67 = h6 < h7 ? h6 : h7;
            unsigned ma = m01 < m23 ? m01 : m23, mb = m45 < m67 ? m45 : m67;
            const unsigned v = ma < mb ? ma : mb;
            op[k] = (unsigned short)(v & 0xFFFu);
            if (v == h0) { p0++; h0 = p0 < 12 ? LRD(0, p0) : 0xFFFFFFFFu; }
            else if (v == h1) { p1++; h1 = p1 < 12 ? LRD(1, p1) : 0xFFFFFFFFu; }
            else if (v == h2) { p2++; h2 = p2 < 12 ? LRD(2, p2) : 0xFFFFFFFFu; }
            else if (v == h3) { p3++; h3 = p3 < 12 ? LRD(3, p3) : 0xFFFFFFFFu; }
            else if (v == h4) { p4++; h4 = p4 < 12 ? LRD(4, p4) : 0xFFFFFFFFu; }
            else if (v == h5) { p5++; h5 = p5 < 12 ? LRD(5, p5) : 0xFFFFFFFFu; }
            else if (v == h6) { p6++; h6 = p6 < 12 ? LRD(6, p6) : 0xFFFFFFFFu; }
            else              { p7++; h7 = p7 < 12 ? LRD(7, p7) : 0xFFFFFFFFu; }
        }
        #undef LRD
    }
}

// ---------------------------------------------------------------------------
// K2: fused edge MLP.  r8 structure (fp8 layer 3, no barriers, no spills)
// with the B-prefetch fixed: w3f8 fragments are contiguous per (cb,ks), so
// each is ONE coalesced global_load_dwordx2 straight into the u64 consumed
// by the MFMA a full half-chunk later — no packing VALU, waitcnt deferred
// behind the previous chunk's 16 MFMAs.
// ---------------------------------------------------------------------------
__global__ __launch_bounds__(256, 2) void mlp_kernel(
    const float* __restrict__ x, const unsigned short* __restrict__ idxb,
    const float* __restrict__ w1, const float* __restrict__ b1,
    const float* __restrict__ b2,
    const bf16_t* __restrict__ w2sw, const unsigned char* __restrict__ w3f8,
    unsigned* __restrict__ g_enc)
{
    __shared__ __align__(16) unsigned char h2l[256 * 128];  // 32768 B, fp8, swizzled
    __shared__ unsigned gl[1024];                           // 4096 B
    __shared__ __align__(16) float4 w1l[64];                // 1024 B

    const int tid = threadIdx.x;
    const int b   = blockIdx.x >> 9;          // 512 blocks per batch
    const int p0  = (blockIdx.x & 511) * 8;   // first point
    const float* xb = x + b * 3 * N_;

    const int wv = tid >> 6;
    const int l  = tid & 63;
    const int lm = l & 31;
    const int hi = l >> 5;

    for (int i = tid; i < 1024; i += 256) gl[i] = 0u;
    if (tid < 64)
        w1l[tid] = make_float4(w1[tid * 3], w1[tid * 3 + 1], w1[tid * 3 + 2], b1[tid]);
    __syncthreads();

    // ---- layer 1 (VALU) -> A1 frags (bf16) ----
    bf16x8 a1[2][4];   // [mt][ks]; A[m=lm][k=ks*16+hi*8+jj]
    float d0[2], d1[2], d2[2];
    #pragma unroll
    for (int mt = 0; mt < 2; mt++) {
        const int pp = p0 + wv * 2 + mt;                 // wave-uniform
        const int j  = idxb[((size_t)(b * N_ + pp)) * K_ + lm];
        d0[mt] = xb[j]          - xb[pp];
        d1[mt] = xb[N_ + j]     - xb[N_ + pp];
        d2[mt] = xb[2 * N_ + j] - xb[2 * N_ + pp];
    }
    #pragma unroll
    for (int ks = 0; ks < 4; ks++)
        #pragma unroll
        for (int jj = 0; jj < 8; jj++) {
            const float4 w = w1l[ks * 16 + hi * 8 + jj];
            #pragma unroll
            for (int mt = 0; mt < 2; mt++)
                a1[mt][ks][jj] = (bf16_t)fmaxf(
                    fmaf(w.z, d2[mt], fmaf(w.y, d1[mt], fmaf(w.x, d0[mt], w.w))), 0.f);
        }

    // ---- layer 2 (MFMA 32x32x16 bf16), 2x2 (np,nt) passes; epilogue
    //      quantizes h2*256 to fp8 into swizzled LDS (8-byte granules) ----
    #pragma unroll
    for (int np = 0; np < 2; np++)
        #pragma unroll
        for (int nt = 0; nt < 2; nt++) {
            floatx16 acc2[2];
            acc2[0] = (floatx16)0.f; acc2[1] = (floatx16)0.f;
            #pragma unroll
            for (int ks = 0; ks < 4; ks++) {
                const bf16x8 bw2 = *(const bf16x8*)&w2sw[(((np * 2 + nt) * 4 + ks) * 64 + l) * 8];
                acc2[0] = __builtin_amdgcn_mfma_f32_32x32x16_bf16(a1[0][ks], bw2, acc2[0], 0, 0, 0);
                acc2[1] = __builtin_amdgcn_mfma_f32_32x32x16_bf16(a1[1][ks], bw2, acc2[1], 0, 0, 0);
            }
            const int col = np * 64 + nt * 32 + lm;
            const float bias = b2[col];
            const int gcol = col >> 3, cb7 = col & 7;
            #pragma unroll
            for (int mt = 0; mt < 2; mt++)
                #pragma unroll
                for (int reg = 0; reg < 16; reg++) {
                    const int row = wv * 64 + mt * 32 + (reg & 3) + 8 * (reg >> 2) + 4 * hi;
                    __hip_fp8_e4m3 t(fmaxf(acc2[mt][reg] + bias, 0.f) * 256.0f);
                    h2l[row * 128 + ((gcol ^ (row & 15)) << 3) + cb7] = t.__x;
                }
        }

    // ---- A3 frags (fp8, 8 B/lane): load once, hold for all 32 chunks ----
    u64 a3[2][8];   // [mt][ks]; A[m=lm][k=ks*16+hi*8+jj]
    #pragma unroll
    for (int mt = 0; mt < 2; mt++)
        #pragma unroll
        for (int ks = 0; ks < 8; ks++) {
            const int R = wv * 64 + mt * 32 + lm;
            const int g = ks * 2 + hi;
            a3[mt][ks] = *(const u64*)&h2l[R * 128 + ((g ^ (R & 15)) << 3)];
        }

    // ---- layer 3: 32 chunks of 32 channels; fp8 MFMA; B loaded directly
    //      as coalesced u64 (dwordx2) into the next half-chunk's registers —
    //      no packing, waitcnt hidden behind current chunk's MFMAs ----
    u64 bwA[8], bwB[8];
    #pragma unroll
    for (int ks = 0; ks < 8; ks++)
        bwA[ks] = *(const u64*)&w3f8[(size_t)(ks * 512 + l * 8)];

    #pragma unroll 1
    for (int cc = 0; cc < 16; cc++) {
        #pragma unroll
        for (int half = 0; half < 2; half++) {
            const int cb = cc * 2 + half;
            u64* cur = half ? bwB : bwA;
            u64* nxt = half ? bwA : bwB;
            if (cb < 31) {
                #pragma unroll
                for (int ks = 0; ks < 8; ks++)
                    nxt[ks] = *(const u64*)&w3f8[(size_t)(((cb + 1) * 8 + ks) * 512 + l * 8)];
            }
            floatx16 acc3[2];
            acc3[0] = (floatx16)0.f; acc3[1] = (floatx16)0.f;
            #pragma unroll
            for (int ks = 0; ks < 8; ks++) {
                acc3[0] = __builtin_amdgcn_mfma_f32_32x32x16_fp8_fp8(
                    (long long)a3[0][ks], (long long)cur[ks], acc3[0], 0, 0, 0);
                acc3[1] = __builtin_amdgcn_mfma_f32_32x32x16_fp8_fp8(
                    (long long)a3[1][ks], (long long)cur[ks], acc3[1], 0, 0, 0);
            }
            // depth-5 parallel max tree, then undo the 256*16 scaling
            float t16[16];
            #pragma unroll
            for (int i = 0; i < 16; i++) t16[i] = fmaxf(acc3[0][i], acc3[1][i]);
            float t8[8];
            #pragma unroll
            for (int i = 0; i < 8; i++) t8[i] = fmaxf(t16[i], t16[i + 8]);
            float t4[4];
            #pragma unroll
            for (int i = 0; i < 4; i++) t4[i] = fmaxf(t8[i], t8[i + 4]);
            float m = fmaxf(fmaxf(t4[0], t4[1]), fmaxf(t4[2], t4[3]));
            m = fmaxf(m, __shfl_xor(m, 32)) * 2.44140625e-4f;   // 1/4096
            if (hi == 0) atomicMax(&gl[cb * 32 + lm], enc_f(m));
        }
    }

    __syncthreads();
    for (int i = tid; i < 1024; i += 256)
        atomicMax(&g_enc[b * 1024 + i], gl[i]);
}

// ---------------------------------------------------------------------------
// K3: FC head per batch. grid 16 x 256.
// ---------------------------------------------------------------------------
__global__ __launch_bounds__(256) void head_kernel(
    const unsigned* __restrict__ g_enc, const float* __restrict__ b3,
    const float* __restrict__ fw1, const float* __restrict__ fb1,
    const float* __restrict__ fw2, const float* __restrict__ fb2,
    const float* __restrict__ fw3, const float* __restrict__ fb3,
    float* __restrict__ tmat)
{
    __shared__ __align__(16) float g[1024];
    __shared__ __align__(16) float f1[512];
    __shared__ __align__(16) float f2[256];
    const int t = threadIdx.x, b = blockIdx.x;

    for (int i = t; i < 1024; i += 256)
        g[i] = fmaxf(dec_f(g_enc[b * 1024 + i]) + b3[i], 0.f);
    __syncthreads();

    for (int o = t; o < 512; o += 256) {
        const float4* wr = (const float4*)(fw1 + (size_t)o * 1024);
        const float4* gv = (const float4*)g;
        float acc = fb1[o];
        for (int i = 0; i < 256; i++) {
            float4 a = wr[i], c = gv[i];
            acc = fmaf(a.x, c.x, acc); acc = fmaf(a.y, c.y, acc);
            acc = fmaf(a.z, c.z, acc); acc = fmaf(a.w, c.w, acc);
        }
        f1[o] = fmaxf(acc, 0.f);
    }
    __syncthreads();
    {
        const int o = t;
        const float4* wr = (const float4*)(fw2 + (size_t)o * 512);
        const float4* fv = (const float4*)f1;
        float acc = fb2[o];
        for (int i = 0; i < 128; i++) {
            float4 a = wr[i], c = fv[i];
            acc = fmaf(a.x, c.x, acc); acc = fmaf(a.y, c.y, acc);
            acc = fmaf(a.z, c.z, acc); acc = fmaf(a.w, c.w, acc);
        }
        f2[o] = fmaxf(acc, 0.f);
    }
    __syncthreads();
    if (t < 9) {
        const float4* wr = (const float4*)(fw3 + (size_t)t * 256);
        const float4* fv = (const float4*)f2;
        float acc = fb3[t];
        for (int i = 0; i < 64; i++) {
            float4 a = wr[i], c = fv[i];
            acc = fmaf(a.x, c.x, acc); acc = fmaf(a.y, c.y, acc);
            acc = fmaf(a.z, c.z, acc); acc = fmaf(a.w, c.w, acc);
        }
        if (t == 0 || t == 4 || t == 8) acc += 1.f;
        tmat[b * 9 + t] = acc;
    }
}

// ---------------------------------------------------------------------------
// K4: out[b][d][n] = sum_c x[b][c][n] * t[b][c][d].  grid 256 x 256.
// ---------------------------------------------------------------------------
__global__ __launch_bounds__(256) void out_kernel(
    const float* __restrict__ x, const float* __restrict__ tmat,
    float* __restrict__ out)
{
    const int gid = blockIdx.x * 256 + threadIdx.x;
    const int b = gid >> 12, n = gid & 4095;
    const float* T = tmat + b * 9;
    const float x0 = x[b * 12288 + n];
    const float x1 = x[b * 12288 + 4096 + n];
    const float x2 = x[b * 12288 + 8192 + n];
    #pragma unroll
    for (int d = 0; d < 3; d++)
        out[b * 12288 + d * 4096 + n] =
            fmaf(x2, T[6 + d], fmaf(x1, T[3 + d], x0 * T[d]));
}

extern "C" void kernel_launch(void* const* d_in, const int* in_sizes, int n_in,
                              void* d_out, int out_size, void* d_ws, size_t ws_size,
                              hipStream_t stream) {
    const float* x   = (const float*)d_in[0];
    const float* w1  = (const float*)d_in[1];
    const float* b1  = (const float*)d_in[2];
    const float* w2  = (const float*)d_in[3];
    const float* b2  = (const float*)d_in[4];
    const float* w3  = (const float*)d_in[5];
    const float* b3  = (const float*)d_in[6];
    const float* fw1 = (const float*)d_in[7];
    const float* fb1 = (const float*)d_in[8];
    const float* fw2 = (const float*)d_in[9];
    const float* fb2 = (const float*)d_in[10];
    const float* fw3 = (const float*)d_in[11];
    const float* fb3 = (const float*)d_in[12];
    float* out = (float*)d_out;

    char* ws = (char*)d_ws;
    unsigned short* idxb = (unsigned short*)ws;
    unsigned* g_enc = (unsigned*)(ws + 4194304);
    unsigned char* w3f8 = (unsigned char*)(ws + 4259840);
    bf16_t* w2sw = (bf16_t*)(ws + 4390912);
    float* tmat  = (float*)(ws + 4407296);

    knn_kernel<<<1024, 512, 0, stream>>>(x, w3, w2, idxb, g_enc, w3f8, w2sw);
    mlp_kernel<<<8192, 256, 0, stream>>>(x, idxb, w1, b1, b2, w2sw, w3f8, g_enc);
    head_kernel<<<16, 256, 0, stream>>>(g_enc, b3, fw1, fb1, fw2, fb2, fw3, fb3, tmat);
    out_kernel<<<256, 256, 0, stream>>>(x, tmat, out);
}

// Round 10
// 774.498 us; speedup vs baseline: 1.0488x; 1.0488x over previous
//
#include <hip/hip_runtime.h>
#include <hip/hip_fp8.h>

typedef __bf16 bf16_t;
typedef __bf16 bf16x8 __attribute__((ext_vector_type(8)));
typedef float floatx16 __attribute__((ext_vector_type(16)));
typedef unsigned long long u64;

#define B_ 16
#define N_ 4096
#define K_ 32

// ws layout (bytes):
//   idx   u16 [16][4096][32]         @ 0        (4194304)
//   g_enc u32 [16][1024]             @ 4194304  (65536)
//   w3f8  fp8 frag-major [131072]    @ 4259840  (131072)   (= w3 * 16)
//   w2sw  bf16 frag-major [8192]     @ 4390912  (16384)
//   tmat  f32 [16][9]                @ 4407296  (576)

__device__ __forceinline__ unsigned enc_f(float f) {
    unsigned u = __float_as_uint(f);
    return (u & 0x80000000u) ? ~u : (u | 0x80000000u);
}
__device__ __forceinline__ float dec_f(unsigned e) {
    return __uint_as_float((e & 0x80000000u) ? (e & 0x7fffffffu) : ~e);
}

// ---------------------------------------------------------------------------
// K1: kNN top-32 (r8 core). 8 threads/query, register top-12, med3-chain
// insert, 8-way LDS tournament merge. grid 1024 x 512.
// Side jobs: zero g_enc, build fp8 frag-major w3f8 (x16, r8 16-byte-pair
// layout: uint4 = ks pair) + bf16 w2sw.
// ---------------------------------------------------------------------------
__global__ __launch_bounds__(512, 4) void knn_kernel(
    const float* __restrict__ x, const float* __restrict__ w3,
    const float* __restrict__ w2, unsigned short* __restrict__ idxb,
    unsigned* __restrict__ g_enc, unsigned char* __restrict__ w3f8,
    bf16_t* __restrict__ w2sw)
{
    __shared__ __align__(16) float4 cand[8 * 513];   // 65664 B
    unsigned* lists = (unsigned*)cand;               // reused after scan
    const int tid = threadIdx.x;
    const int bid = blockIdx.x;  // 1024 blocks

    // side jobs.  w3f8 byte o: jj=o&7, half=(o>>3)&1, l=(o>>4)&63,
    // kp=(o>>10)&3, cb=o>>12; ks=kp*2+half, lm=l&31, hi=l>>5;
    // value = fp8(16 * w3[cb*32+lm][ks*16+hi*8+jj]).
    {
        const int g = bid * 512 + tid;
        if (g < 131072) {
            const int jj = g & 7, half = (g >> 3) & 1, lI = (g >> 4) & 63;
            const int kp = (g >> 10) & 3, cb = g >> 12;
            const int ks = kp * 2 + half, lmI = lI & 31, hiI = lI >> 5;
            __hip_fp8_e4m3 t(16.0f * w3[(cb * 32 + lmI) * 128 + ks * 16 + hiI * 8 + jj]);
            w3f8[g] = t.__x;
        } else if (g < 139264) {
            const int o = g - 131072;
            const int f = o >> 9, r = o & 511, lI = r >> 3, jj = r & 7;
            const int ks = f & 3, nb = f >> 2, lmI = lI & 31, hiI = lI >> 5;
            w2sw[o] = (bf16_t)w2[(nb * 32 + lmI) * 64 + ks * 16 + hiI * 8 + jj];
        } else if (g < 155648) {
            g_enc[g - 139264] = 0u;
        }
    }

    const int b  = bid >> 6;                    // 64 blocks per batch
    const int q  = tid >> 3;                    // local query 0..63
    const int n  = (bid & 63) * 64 + q;         // global query index
    const int t  = tid & 7;                     // candidate chunk
    const float* xb = x + b * 3 * N_;

    for (int j = tid; j < N_; j += 512) {
        float cx = xb[j], cy = xb[N_ + j], cz = xb[2 * N_ + j];
        cand[j + (j >> 9)] = make_float4(-2.f * cx, -2.f * cy, -2.f * cz,
                                         fmaf(cx, cx, fmaf(cy, cy, cz * cz)));
    }
    __syncthreads();

    const float xi0 = xb[n], xi1 = xb[N_ + n], xi2 = xb[2 * N_ + n];
    const float xisq = fmaf(xi0, xi0, fmaf(xi1, xi1, xi2 * xi2));

    unsigned r[12];
    #pragma unroll
    for (int s = 0; s < 12; s++) r[s] = 0x7F7FFFFFu;   // FLT_MAX sentinel

    const int j0 = t * 512;
    const int pb = t * 513;
    #pragma unroll 8
    for (int jj = 0; jj < 512; jj++) {
        const float4 c = cand[pb + jj];
        const float d = fmaf(c.z, xi2, fmaf(c.y, xi1, fmaf(c.x, xi0, c.w)));
        const float df = fmaxf(d + xisq, 0.f);
        const unsigned key = (__float_as_uint(df) & 0xFFFFF000u) | (unsigned)(j0 + jj);
        #pragma unroll
        for (int s = 11; s >= 1; s--) {
            const unsigned hv = r[s - 1] > key ? r[s - 1] : key;
            r[s] = r[s] < hv ? r[s] : hv;           // med3
        }
        r[0] = r[0] < key ? r[0] : key;
    }
    __syncthreads();   // cand reads done; reuse LDS for lists

    #pragma unroll
    for (int k = 0; k < 12; k++) lists[tid * 13 + k] = r[k];   // stride 13: conflict-free
    __syncthreads();

    if (tid < 64) {
        #define LRD(i, p) lists[(tid * 8 + (i)) * 13 + (p)]
        unsigned h0 = LRD(0, 0), h1 = LRD(1, 0), h2 = LRD(2, 0), h3 = LRD(3, 0);
        unsigned h4 = LRD(4, 0), h5 = LRD(5, 0), h6 = LRD(6, 0), h7 = LRD(7, 0);
        int p0 = 0, p1 = 0, p2 = 0, p3 = 0, p4 = 0, p5 = 0, p6 = 0, p7 = 0;
        const int nq = (bid & 63) * 64 + tid;
        unsigned short* op = idxb + ((size_t)(b * N_ + nq)) * K_;
        #pragma unroll 1
        for (int k = 0; k < K_; k++) {
            unsigned m01 = h0 < h1 ? h0 : h1, m23 = h2 < h3 ? h2 : h3;
            unsigned m45 = h4 < h5 ? h4 : h5, m67 = h6 < h7 ? h6 : h7;
            unsigned ma = m01 < m23 ? m01 : m23, mb = m45 < m67 ? m45 : m67;
            const unsigned v = ma < mb ? ma : mb;
            op[k] = (unsigned short)(v & 0xFFFu);
            if (v == h0) { p0++; h0 = p0 < 12 ? LRD(0, p0) : 0xFFFFFFFFu; }
            else if (v == h1) { p1++; h1 = p1 < 12 ? LRD(1, p1) : 0xFFFFFFFFu; }
            else if (v == h2) { p2++; h2 = p2 < 12 ? LRD(2, p2) : 0xFFFFFFFFu; }
            else if (v == h3) { p3++; h3 = p3 < 12 ? LRD(3, p3) : 0xFFFFFFFFu; }
            else if (v == h4) { p4++; h4 = p4 < 12 ? LRD(4, p4) : 0xFFFFFFFFu; }
            else if (v == h5) { p5++; h5 = p5 < 12 ? LRD(5, p5) : 0xFFFFFFFFu; }
            else if (v == h6) { p6++; h6 = p6 < 12 ? LRD(6, p6) : 0xFFFFFFFFu; }
            else              { p7++; h7 = p7 < 12 ? LRD(7, p7) : 0xFFFFFFFFu; }
        }
        #undef LRD
    }
}

// ---------------------------------------------------------------------------
// K2: fused edge MLP.  r8 structure with layer-3 CHANNEL-SPLIT across wave
// pairs: waves 0,1 process chunks 0-15, waves 2,3 chunks 16-31; each wave
// owns 128 edges (4 m-tiles) read from the shared h2l after one barrier.
// Per chunk per CU only 4 waves fetch a given w3 chunk -> L1 B-traffic
// halves while MFMA per chunk doubles (ratio 2:1 in favor of MFMA).
// fp8 MFMA, uint4 B prefetch (r8-proven), depth-6 tree epilogue.
// ---------------------------------------------------------------------------
__global__ __launch_bounds__(256, 2) void mlp_kernel(
    const float* __restrict__ x, const unsigned short* __restrict__ idxb,
    const float* __restrict__ w1, const float* __restrict__ b1,
    const float* __restrict__ b2,
    const bf16_t* __restrict__ w2sw, const unsigned char* __restrict__ w3f8,
    unsigned* __restrict__ g_enc)
{
    __shared__ __align__(16) unsigned char h2l[256 * 128];  // 32768 B, fp8, swizzled
    __shared__ unsigned gl[1024];                           // 4096 B
    __shared__ __align__(16) float4 w1l[64];                // 1024 B

    const int tid = threadIdx.x;
    const int b   = blockIdx.x >> 9;          // 512 blocks per batch
    const int p0  = (blockIdx.x & 511) * 8;   // first point
    const float* xb = x + b * 3 * N_;

    const int wv = tid >> 6;
    const int l  = tid & 63;
    const int lm = l & 31;
    const int hi = l >> 5;

    for (int i = tid; i < 1024; i += 256) gl[i] = 0u;
    if (tid < 64)
        w1l[tid] = make_float4(w1[tid * 3], w1[tid * 3 + 1], w1[tid * 3 + 2], b1[tid]);
    __syncthreads();

    // ---- layer 1 (VALU) -> A1 frags (bf16) ----
    bf16x8 a1[2][4];   // [mt][ks]; A[m=lm][k=ks*16+hi*8+jj]
    float d0[2], d1[2], d2[2];
    #pragma unroll
    for (int mt = 0; mt < 2; mt++) {
        const int pp = p0 + wv * 2 + mt;                 // wave-uniform
        const int j  = idxb[((size_t)(b * N_ + pp)) * K_ + lm];
        d0[mt] = xb[j]          - xb[pp];
        d1[mt] = xb[N_ + j]     - xb[N_ + pp];
        d2[mt] = xb[2 * N_ + j] - xb[2 * N_ + pp];
    }
    #pragma unroll
    for (int ks = 0; ks < 4; ks++)
        #pragma unroll
        for (int jj = 0; jj < 8; jj++) {
            const float4 w = w1l[ks * 16 + hi * 8 + jj];
            #pragma unroll
            for (int mt = 0; mt < 2; mt++)
                a1[mt][ks][jj] = (bf16_t)fmaxf(
                    fmaf(w.z, d2[mt], fmaf(w.y, d1[mt], fmaf(w.x, d0[mt], w.w))), 0.f);
        }

    // ---- layer 2 (MFMA 32x32x16 bf16), 2x2 (np,nt) passes; epilogue
    //      quantizes h2*256 to fp8 into swizzled LDS (8-byte granules) ----
    #pragma unroll
    for (int np = 0; np < 2; np++)
        #pragma unroll
        for (int nt = 0; nt < 2; nt++) {
            floatx16 acc2[2];
            acc2[0] = (floatx16)0.f; acc2[1] = (floatx16)0.f;
            #pragma unroll
            for (int ks = 0; ks < 4; ks++) {
                const bf16x8 bw2 = *(const bf16x8*)&w2sw[(((np * 2 + nt) * 4 + ks) * 64 + l) * 8];
                acc2[0] = __builtin_amdgcn_mfma_f32_32x32x16_bf16(a1[0][ks], bw2, acc2[0], 0, 0, 0);
                acc2[1] = __builtin_amdgcn_mfma_f32_32x32x16_bf16(a1[1][ks], bw2, acc2[1], 0, 0, 0);
            }
            const int col = np * 64 + nt * 32 + lm;
            const float bias = b2[col];
            const int gcol = col >> 3, cb7 = col & 7;
            #pragma unroll
            for (int mt = 0; mt < 2; mt++)
                #pragma unroll
                for (int reg = 0; reg < 16; reg++) {
                    const int row = wv * 64 + mt * 32 + (reg & 3) + 8 * (reg >> 2) + 4 * hi;
                    __hip_fp8_e4m3 t(fmaxf(acc2[mt][reg] + bias, 0.f) * 256.0f);
                    h2l[row * 128 + ((gcol ^ (row & 15)) << 3) + cb7] = t.__x;
                }
        }
    __syncthreads();   // h2l complete — cross-wave reads follow

    // ---- A3 frags (fp8, 8 B/lane): this wave's 128-edge half ----
    const int mh  = wv & 1;          // m-half: edges [mh*128, mh*128+128)
    const int cb0 = (wv >> 1) * 16;  // chunk range: [cb0, cb0+16)
    u64 a3[4][8];   // [mt][ks]; A[m=lm][k=ks*16+hi*8+jj]
    #pragma unroll
    for (int mt = 0; mt < 4; mt++)
        #pragma unroll
        for (int ks = 0; ks < 8; ks++) {
            const int R = mh * 128 + mt * 32 + lm;
            const int g = ks * 2 + hi;
            a3[mt][ks] = *(const u64*)&h2l[R * 128 + ((g ^ (R & 15)) << 3)];
        }

    // ---- layer 3: 16 chunks of 32 channels per wave; fp8 MFMA, uint4 B
    //      prefetch double-buffered in regs, NO barriers ----
    const uint4* w3v = (const uint4*)w3f8;   // 16 B = 2 frags (ks pair)
    u64 bwA[8], bwB[8];
    #pragma unroll
    for (int kp = 0; kp < 4; kp++) {
        const uint4 v = w3v[(cb0 * 4 + kp) * 64 + l];
        bwA[2 * kp]     = ((u64)v.y << 32) | v.x;
        bwA[2 * kp + 1] = ((u64)v.w << 32) | v.z;
    }

    #pragma unroll 1
    for (int cc = 0; cc < 8; cc++) {
        #pragma unroll
        for (int half = 0; half < 2; half++) {
            const int ci = cc * 2 + half;       // 0..15
            const int cb = cb0 + ci;
            u64* cur = half ? bwB : bwA;
            u64* nxt = half ? bwA : bwB;
            if (ci < 15) {
                #pragma unroll
                for (int kp = 0; kp < 4; kp++) {
                    const uint4 v = w3v[((cb + 1) * 4 + kp) * 64 + l];
                    nxt[2 * kp]     = ((u64)v.y << 32) | v.x;
                    nxt[2 * kp + 1] = ((u64)v.w << 32) | v.z;
                }
            }
            floatx16 acc3[4];
            acc3[0] = (floatx16)0.f; acc3[1] = (floatx16)0.f;
            acc3[2] = (floatx16)0.f; acc3[3] = (floatx16)0.f;
            #pragma unroll
            for (int ks = 0; ks < 8; ks++) {
                #pragma unroll
                for (int mt = 0; mt < 4; mt++)
                    acc3[mt] = __builtin_amdgcn_mfma_f32_32x32x16_fp8_fp8(
                        (long long)a3[mt][ks], (long long)cur[ks], acc3[mt], 0, 0, 0);
            }
            // depth-6 parallel max tree over 64 values, undo 256*16 scaling
            float t16[16];
            #pragma unroll
            for (int i = 0; i < 16; i++)
                t16[i] = fmaxf(fmaxf(acc3[0][i], acc3[1][i]),
                               fmaxf(acc3[2][i], acc3[3][i]));
            float t8[8];
            #pragma unroll
            for (int i = 0; i < 8; i++) t8[i] = fmaxf(t16[i], t16[i + 8]);
            float t4[4];
            #pragma unroll
            for (int i = 0; i < 4; i++) t4[i] = fmaxf(t8[i], t8[i + 4]);
            float m = fmaxf(fmaxf(t4[0], t4[1]), fmaxf(t4[2], t4[3]));
            m = fmaxf(m, __shfl_xor(m, 32)) * 2.44140625e-4f;   // 1/4096
            if (hi == 0) atomicMax(&gl[cb * 32 + lm], enc_f(m));
        }
    }

    __syncthreads();
    for (int i = tid; i < 1024; i += 256)
        atomicMax(&g_enc[b * 1024 + i], gl[i]);
}

// ---------------------------------------------------------------------------
// K3: FC head per batch. grid 16 x 256.
// ---------------------------------------------------------------------------
__global__ __launch_bounds__(256) void head_kernel(
    const unsigned* __restrict__ g_enc, const float* __restrict__ b3,
    const float* __restrict__ fw1, const float* __restrict__ fb1,
    const float* __restrict__ fw2, const float* __restrict__ fb2,
    const float* __restrict__ fw3, const float* __restrict__ fb3,
    float* __restrict__ tmat)
{
    __shared__ __align__(16) float g[1024];
    __shared__ __align__(16) float f1[512];
    __shared__ __align__(16) float f2[256];
    const int t = threadIdx.x, b = blockIdx.x;

    for (int i = t; i < 1024; i += 256)
        g[i] = fmaxf(dec_f(g_enc[b * 1024 + i]) + b3[i], 0.f);
    __syncthreads();

    for (int o = t; o < 512; o += 256) {
        const float4* wr = (const float4*)(fw1 + (size_t)o * 1024);
        const float4* gv = (const float4*)g;
        float acc = fb1[o];
        for (int i = 0; i < 256; i++) {
            float4 a = wr[i], c = gv[i];
            acc = fmaf(a.x, c.x, acc); acc = fmaf(a.y, c.y, acc);
            acc = fmaf(a.z, c.z, acc); acc = fmaf(a.w, c.w, acc);
        }
        f1[o] = fmaxf(acc, 0.f);
    }
    __syncthreads();
    {
        const int o = t;
        const float4* wr = (const float4*)(fw2 + (size_t)o * 512);
        const float4* fv = (const float4*)f1;
        float acc = fb2[o];
        for (int i = 0; i < 128; i++) {
            float4 a = wr[i], c = fv[i];
            acc = fmaf(a.x, c.x, acc); acc = fmaf(a.y, c.y, acc);
            acc = fmaf(a.z, c.z, acc); acc = fmaf(a.w, c.w, acc);
        }
        f2[o] = fmaxf(acc, 0.f);
    }
    __syncthreads();
    if (t < 9) {
        const float4* wr = (const float4*)(fw3 + (size_t)t * 256);
        const float4* fv = (const float4*)f2;
        float acc = fb3[t];
        for (int i = 0; i < 64; i++) {
            float4 a = wr[i], c = fv[i];
            acc = fmaf(a.x, c.x, acc); acc = fmaf(a.y, c.y, acc);
            acc = fmaf(a.z, c.z, acc); acc = fmaf(a.w, c.w, acc);
        }
        if (t == 0 || t == 4 || t == 8) acc += 1.f;
        tmat[b * 9 + t] = acc;
    }
}

// ---------------------------------------------------------------------------
// K4: out[b][d][n] = sum_c x[b][c][n] * t[b][c][d].  grid 256 x 256.
// ---------------------------------------------------------------------------
__global__ __launch_bounds__(256) void out_kernel(
    const float* __restrict__ x, const float* __restrict__ tmat,
    float* __restrict__ out)
{
    const int gid = blockIdx.x * 256 + threadIdx.x;
    const int b = gid >> 12, n = gid & 4095;
    const float* T = tmat + b * 9;
    const float x0 = x[b * 12288 + n];
    const float x1 = x[b * 12288 + 4096 + n];
    const float x2 = x[b * 12288 + 8192 + n];
    #pragma unroll
    for (int d = 0; d < 3; d++)
        out[b * 12288 + d * 4096 + n] =
            fmaf(x2, T[6 + d], fmaf(x1, T[3 + d], x0 * T[d]));
}

extern "C" void kernel_launch(void* const* d_in, const int* in_sizes, int n_in,
                              void* d_out, int out_size, void* d_ws, size_t ws_size,
                              hipStream_t stream) {
    const float* x   = (const float*)d_in[0];
    const float* w1  = (const float*)d_in[1];
    const float* b1  = (const float*)d_in[2];
    const float* w2  = (const float*)d_in[3];
    const float* b2  = (const float*)d_in[4];
    const float* w3  = (const float*)d_in[5];
    const float* b3  = (const float*)d_in[6];
    const float* fw1 = (const float*)d_in[7];
    const float* fb1 = (const float*)d_in[8];
    const float* fw2 = (const float*)d_in[9];
    const float* fb2 = (const float*)d_in[10];
    const float* fw3 = (const float*)d_in[11];
    const float* fb3 = (const float*)d_in[12];
    float* out = (float*)d_out;

    char* ws = (char*)d_ws;
    unsigned short* idxb = (unsigned short*)ws;
    unsigned* g_enc = (unsigned*)(ws + 4194304);
    unsigned char* w3f8 = (unsigned char*)(ws + 4259840);
    bf16_t* w2sw = (bf16_t*)(ws + 4390912);
    float* tmat  = (float*)(ws + 4407296);

    knn_kernel<<<1024, 512, 0, stream>>>(x, w3, w2, idxb, g_enc, w3f8, w2sw);
    mlp_kernel<<<8192, 256, 0, stream>>>(x, idxb, w1, b1, b2, w2sw, w3f8, g_enc);
    head_kernel<<<16, 256, 0, stream>>>(g_enc, b3, fw1, fb1, fw2, fb2, fw3, fb3, tmat);
    out_kernel<<<256, 256, 0, stream>>>(x, tmat, out);
}

// Round 12
// 673.008 us; speedup vs baseline: 1.2070x; 1.1508x over previous
//
#include <hip/hip_runtime.h>
#include <hip/hip_fp8.h>

typedef __bf16 bf16_t;
typedef __bf16 bf16x8 __attribute__((ext_vector_type(8)));
typedef float floatx16 __attribute__((ext_vector_type(16)));
typedef int intx8 __attribute__((ext_vector_type(8)));
typedef unsigned long long u64;

#define B_ 16
#define N_ 4096
#define K_ 32

// ws layout (bytes):
//   idx   u16 [16][4096][32]         @ 0        (4194304)
//   g_enc u32 [16][1024]             @ 4194304  (65536)
//   w3f8  fp8 frag-major [131072]    @ 4259840  (131072)   (= w3 * 16)
//   w2sw  bf16 frag-major [8192]     @ 4390912  (16384)
//   tmat  f32 [16][9]                @ 4407296  (576)

__device__ __forceinline__ unsigned enc_f(float f) {
    unsigned u = __float_as_uint(f);
    return (u & 0x80000000u) ? ~u : (u | 0x80000000u);
}
__device__ __forceinline__ float dec_f(unsigned e) {
    return __uint_as_float((e & 0x80000000u) ? (e & 0x7fffffffu) : ~e);
}

// ---------------------------------------------------------------------------
// K1: kNN top-32 (r8 core, unchanged). 8 threads/query, register top-12,
// med3-chain insert, 8-way LDS tournament merge. grid 1024 x 512.
// Side jobs: zero g_enc, build fp8 frag-major w3f8 (x16, 16-byte ks-pair
// layout) + bf16 w2sw.
// ---------------------------------------------------------------------------
__global__ __launch_bounds__(512, 4) void knn_kernel(
    const float* __restrict__ x, const float* __restrict__ w3,
    const float* __restrict__ w2, unsigned short* __restrict__ idxb,
    unsigned* __restrict__ g_enc, unsigned char* __restrict__ w3f8,
    bf16_t* __restrict__ w2sw)
{
    __shared__ __align__(16) float4 cand[8 * 513];   // 65664 B
    unsigned* lists = (unsigned*)cand;               // reused after scan
    const int tid = threadIdx.x;
    const int bid = blockIdx.x;  // 1024 blocks

    // side jobs.  w3f8 byte o: jj=o&7, half=(o>>3)&1, l=(o>>4)&63,
    // kp=(o>>10)&3, cb=o>>12; ks=kp*2+half, lm=l&31, hi=l>>5;
    // value = fp8(16 * w3[cb*32+lm][ks*16+hi*8+jj]).
    {
        const int g = bid * 512 + tid;
        if (g < 131072) {
            const int jj = g & 7, half = (g >> 3) & 1, lI = (g >> 4) & 63;
            const int kp = (g >> 10) & 3, cb = g >> 12;
            const int ks = kp * 2 + half, lmI = lI & 31, hiI = lI >> 5;
            __hip_fp8_e4m3 t(16.0f * w3[(cb * 32 + lmI) * 128 + ks * 16 + hiI * 8 + jj]);
            w3f8[g] = t.__x;
        } else if (g < 139264) {
            const int o = g - 131072;
            const int f = o >> 9, r = o & 511, lI = r >> 3, jj = r & 7;
            const int ks = f & 3, nb = f >> 2, lmI = lI & 31, hiI = lI >> 5;
            w2sw[o] = (bf16_t)w2[(nb * 32 + lmI) * 64 + ks * 16 + hiI * 8 + jj];
        } else if (g < 155648) {
            g_enc[g - 139264] = 0u;
        }
    }

    const int b  = bid >> 6;                    // 64 blocks per batch
    const int q  = tid >> 3;                    // local query 0..63
    const int n  = (bid & 63) * 64 + q;         // global query index
    const int t  = tid & 7;                     // candidate chunk
    const float* xb = x + b * 3 * N_;

    for (int j = tid; j < N_; j += 512) {
        float cx = xb[j], cy = xb[N_ + j], cz = xb[2 * N_ + j];
        cand[j + (j >> 9)] = make_float4(-2.f * cx, -2.f * cy, -2.f * cz,
                                         fmaf(cx, cx, fmaf(cy, cy, cz * cz)));
    }
    __syncthreads();

    const float xi0 = xb[n], xi1 = xb[N_ + n], xi2 = xb[2 * N_ + n];
    const float xisq = fmaf(xi0, xi0, fmaf(xi1, xi1, xi2 * xi2));

    unsigned r[12];
    #pragma unroll
    for (int s = 0; s < 12; s++) r[s] = 0x7F7FFFFFu;   // FLT_MAX sentinel

    const int j0 = t * 512;
    const int pb = t * 513;
    #pragma unroll 8
    for (int jj = 0; jj < 512; jj++) {
        const float4 c = cand[pb + jj];
        const float d = fmaf(c.z, xi2, fmaf(c.y, xi1, fmaf(c.x, xi0, c.w)));
        const float df = fmaxf(d + xisq, 0.f);
        const unsigned key = (__float_as_uint(df) & 0xFFFFF000u) | (unsigned)(j0 + jj);
        #pragma unroll
        for (int s = 11; s >= 1; s--) {
            const unsigned hv = r[s - 1] > key ? r[s - 1] : key;
            r[s] = r[s] < hv ? r[s] : hv;           // med3
        }
        r[0] = r[0] < key ? r[0] : key;
    }
    __syncthreads();   // cand reads done; reuse LDS for lists

    #pragma unroll
    for (int k = 0; k < 12; k++) lists[tid * 13 + k] = r[k];   // stride 13: conflict-free
    __syncthreads();

    if (tid < 64) {
        #define LRD(i, p) lists[(tid * 8 + (i)) * 13 + (p)]
        unsigned h0 = LRD(0, 0), h1 = LRD(1, 0), h2 = LRD(2, 0), h3 = LRD(3, 0);
        unsigned h4 = LRD(4, 0), h5 = LRD(5, 0), h6 = LRD(6, 0), h7 = LRD(7, 0);
        int p0 = 0, p1 = 0, p2 = 0, p3 = 0, p4 = 0, p5 = 0, p6 = 0, p7 = 0;
        const int nq = (bid & 63) * 64 + tid;
        unsigned short* op = idxb + ((size_t)(b * N_ + nq)) * K_;
        #pragma unroll 1
        for (int k = 0; k < K_; k++) {
            unsigned m01 = h0 < h1 ? h0 : h1, m23 = h2 < h3 ? h2 : h3;
            unsigned m45 = h4 < h5 ? h4 : h5, m67 = h6 < h7 ? h6 : h7;
            unsigned ma = m01 < m23 ? m01 : m23, mb = m45 < m67 ? m45 : m67;
            const unsigned v = ma < mb ? ma : mb;
            op[k] = (unsigned short)(v & 0xFFFu);
            if (v == h0) { p0++; h0 = p0 < 12 ? LRD(0, p0) : 0xFFFFFFFFu; }
            else if (v == h1) { p1++; h1 = p1 < 12 ? LRD(1, p1) : 0xFFFFFFFFu; }
            else if (v == h2) { p2++; h2 = p2 < 12 ? LRD(2, p2) : 0xFFFFFFFFu; }
            else if (v == h3) { p3++; h3 = p3 < 12 ? LRD(3, p3) : 0xFFFFFFFFu; }
            else if (v == h4) { p4++; h4 = p4 < 12 ? LRD(4, p4) : 0xFFFFFFFFu; }
            else if (v == h5) { p5++; h5 = p5 < 12 ? LRD(5, p5) : 0xFFFFFFFFu; }
            else if (v == h6) { p6++; h6 = p6 < 12 ? LRD(6, p6) : 0xFFFFFFFFu; }
            else              { p7++; h7 = p7 < 12 ? LRD(7, p7) : 0xFFFFFFFFu; }
        }
        #undef LRD
    }
}

// ---------------------------------------------------------------------------
// K2: fused edge MLP.  r10 structure (channel-split wave pairs, fp8 data,
// uint4 B prefetch) with layer 3 on the MX-scaled K=64 instruction
// mfma_scale_f32_32x32x64_f8f6f4 (fp8 A/B, scales = 1.0): half the MFMA
// pipe time for identical bytes and identical math.  A/B packed with the
// same per-16 (ks*16+hi*8+jj) convention on both operands — a consistent
// k-permutation is correctness-neutral.
// ---------------------------------------------------------------------------
__global__ __launch_bounds__(256, 2) void mlp_kernel(
    const float* __restrict__ x, const unsigned short* __restrict__ idxb,
    const float* __restrict__ w1, const float* __restrict__ b1,
    const float* __restrict__ b2,
    const bf16_t* __restrict__ w2sw, const unsigned char* __restrict__ w3f8,
    unsigned* __restrict__ g_enc)
{
    __shared__ __align__(16) unsigned char h2l[256 * 128];  // 32768 B, fp8, swizzled
    __shared__ unsigned gl[1024];                           // 4096 B
    __shared__ __align__(16) float4 w1l[64];                // 1024 B

    const int tid = threadIdx.x;
    const int b   = blockIdx.x >> 9;          // 512 blocks per batch
    const int p0  = (blockIdx.x & 511) * 8;   // first point
    const float* xb = x + b * 3 * N_;

    const int wv = tid >> 6;
    const int l  = tid & 63;
    const int lm = l & 31;
    const int hi = l >> 5;

    for (int i = tid; i < 1024; i += 256) gl[i] = 0u;
    if (tid < 64)
        w1l[tid] = make_float4(w1[tid * 3], w1[tid * 3 + 1], w1[tid * 3 + 2], b1[tid]);
    __syncthreads();

    // ---- layer 1 (VALU) -> A1 frags (bf16) ----
    bf16x8 a1[2][4];   // [mt][ks]; A[m=lm][k=ks*16+hi*8+jj]
    float d0[2], d1[2], d2[2];
    #pragma unroll
    for (int mt = 0; mt < 2; mt++) {
        const int pp = p0 + wv * 2 + mt;                 // wave-uniform
        const int j  = idxb[((size_t)(b * N_ + pp)) * K_ + lm];
        d0[mt] = xb[j]          - xb[pp];
        d1[mt] = xb[N_ + j]     - xb[N_ + pp];
        d2[mt] = xb[2 * N_ + j] - xb[2 * N_ + pp];
    }
    #pragma unroll
    for (int ks = 0; ks < 4; ks++)
        #pragma unroll
        for (int jj = 0; jj < 8; jj++) {
            const float4 w = w1l[ks * 16 + hi * 8 + jj];
            #pragma unroll
            for (int mt = 0; mt < 2; mt++)
                a1[mt][ks][jj] = (bf16_t)fmaxf(
                    fmaf(w.z, d2[mt], fmaf(w.y, d1[mt], fmaf(w.x, d0[mt], w.w))), 0.f);
        }

    // ---- layer 2 (MFMA 32x32x16 bf16), 2x2 (np,nt) passes; epilogue
    //      quantizes h2*256 to fp8 into swizzled LDS (8-byte granules) ----
    #pragma unroll
    for (int np = 0; np < 2; np++)
        #pragma unroll
        for (int nt = 0; nt < 2; nt++) {
            floatx16 acc2[2];
            acc2[0] = (floatx16)0.f; acc2[1] = (floatx16)0.f;
            #pragma unroll
            for (int ks = 0; ks < 4; ks++) {
                const bf16x8 bw2 = *(const bf16x8*)&w2sw[(((np * 2 + nt) * 4 + ks) * 64 + l) * 8];
                acc2[0] = __builtin_amdgcn_mfma_f32_32x32x16_bf16(a1[0][ks], bw2, acc2[0], 0, 0, 0);
                acc2[1] = __builtin_amdgcn_mfma_f32_32x32x16_bf16(a1[1][ks], bw2, acc2[1], 0, 0, 0);
            }
            const int col = np * 64 + nt * 32 + lm;
            const float bias = b2[col];
            const int gcol = col >> 3, cb7 = col & 7;
            #pragma unroll
            for (int mt = 0; mt < 2; mt++)
                #pragma unroll
                for (int reg = 0; reg < 16; reg++) {
                    const int row = wv * 64 + mt * 32 + (reg & 3) + 8 * (reg >> 2) + 4 * hi;
                    __hip_fp8_e4m3 t(fmaxf(acc2[mt][reg] + bias, 0.f) * 256.0f);
                    h2l[row * 128 + ((gcol ^ (row & 15)) << 3) + cb7] = t.__x;
                }
        }
    __syncthreads();   // h2l complete — cross-wave reads follow

    // ---- A3 frags packed for K=64 scaled MFMA: intx8 = 4 ks-frags ----
    const int mh  = wv & 1;          // m-half: edges [mh*128, mh*128+128)
    const int cb0 = (wv >> 1) * 16;  // chunk range: [cb0, cb0+16)
    intx8 a3v[4][2];   // [mt][kq]; components 2*ksq..2*ksq+1 = frag ks=kq*4+ksq
    #pragma unroll
    for (int mt = 0; mt < 4; mt++)
        #pragma unroll
        for (int kq = 0; kq < 2; kq++)
            #pragma unroll
            for (int ksq = 0; ksq < 4; ksq++) {
                const int ks = kq * 4 + ksq;
                const int R = mh * 128 + mt * 32 + lm;
                const int g = ks * 2 + hi;
                const u64 v = *(const u64*)&h2l[R * 128 + ((g ^ (R & 15)) << 3)];
                a3v[mt][kq][2 * ksq]     = (int)(unsigned)(v & 0xFFFFFFFFull);
                a3v[mt][kq][2 * ksq + 1] = (int)(unsigned)(v >> 32);
            }

    // ---- layer 3: 16 chunks of 32 channels per wave; scaled fp8 MFMA
    //      (K=64, scales=1.0), uint4 B prefetch double-buffered, NO barriers ----
    const uint4* w3v = (const uint4*)w3f8;   // 16 B = ks pair (kp)
    intx8 bwA[2], bwB[2];
    #pragma unroll
    for (int kp = 0; kp < 4; kp++) {
        const uint4 v = w3v[(cb0 * 4 + kp) * 64 + l];
        bwA[kp >> 1][(kp & 1) * 4 + 0] = (int)v.x;
        bwA[kp >> 1][(kp & 1) * 4 + 1] = (int)v.y;
        bwA[kp >> 1][(kp & 1) * 4 + 2] = (int)v.z;
        bwA[kp >> 1][(kp & 1) * 4 + 3] = (int)v.w;
    }

    #pragma unroll 1
    for (int cc = 0; cc < 8; cc++) {
        #pragma unroll
        for (int half = 0; half < 2; half++) {
            const int ci = cc * 2 + half;       // 0..15
            const int cb = cb0 + ci;
            intx8* cur = half ? bwB : bwA;
            intx8* nxt = half ? bwA : bwB;
            if (ci < 15) {
                #pragma unroll
                for (int kp = 0; kp < 4; kp++) {
                    const uint4 v = w3v[((cb + 1) * 4 + kp) * 64 + l];
                    nxt[kp >> 1][(kp & 1) * 4 + 0] = (int)v.x;
                    nxt[kp >> 1][(kp & 1) * 4 + 1] = (int)v.y;
                    nxt[kp >> 1][(kp & 1) * 4 + 2] = (int)v.z;
                    nxt[kp >> 1][(kp & 1) * 4 + 3] = (int)v.w;
                }
            }
            floatx16 acc3[4];
            acc3[0] = (floatx16)0.f; acc3[1] = (floatx16)0.f;
            acc3[2] = (floatx16)0.f; acc3[3] = (floatx16)0.f;
            #pragma unroll
            for (int kq = 0; kq < 2; kq++)
                #pragma unroll
                for (int mt = 0; mt < 4; mt++)
                    acc3[mt] = __builtin_amdgcn_mfma_scale_f32_32x32x64_f8f6f4(
                        a3v[mt][kq], cur[kq], acc3[mt],
                        0, 0,                      // cbsz=fp8, blgp=fp8
                        0, 0x7F7F7F7F,             // scale A = 1.0 (E8M0 127)
                        0, 0x7F7F7F7F);            // scale B = 1.0
            // depth-6 parallel max tree over 64 values, undo 256*16 scaling
            float t16[16];
            #pragma unroll
            for (int i = 0; i < 16; i++)
                t16[i] = fmaxf(fmaxf(acc3[0][i], acc3[1][i]),
                               fmaxf(acc3[2][i], acc3[3][i]));
            float t8[8];
            #pragma unroll
            for (int i = 0; i < 8; i++) t8[i] = fmaxf(t16[i], t16[i + 8]);
            float t4[4];
            #pragma unroll
            for (int i = 0; i < 4; i++) t4[i] = fmaxf(t8[i], t8[i + 4]);
            float m = fmaxf(fmaxf(t4[0], t4[1]), fmaxf(t4[2], t4[3]));
            m = fmaxf(m, __shfl_xor(m, 32)) * 2.44140625e-4f;   // 1/4096
            if (hi == 0) atomicMax(&gl[cb * 32 + lm], enc_f(m));
        }
    }

    __syncthreads();
    for (int i = tid; i < 1024; i += 256)
        atomicMax(&g_enc[b * 1024 + i], gl[i]);
}

// ---------------------------------------------------------------------------
// K3: FC head per batch. grid 16 x 256.
// ---------------------------------------------------------------------------
__global__ __launch_bounds__(256) void head_kernel(
    const unsigned* __restrict__ g_enc, const float* __restrict__ b3,
    const float* __restrict__ fw1, const float* __restrict__ fb1,
    const float* __restrict__ fw2, const float* __restrict__ fb2,
    const float* __restrict__ fw3, const float* __restrict__ fb3,
    float* __restrict__ tmat)
{
    __shared__ __align__(16) float g[1024];
    __shared__ __align__(16) float f1[512];
    __shared__ __align__(16) float f2[256];
    const int t = threadIdx.x, b = blockIdx.x;

    for (int i = t; i < 1024; i += 256)
        g[i] = fmaxf(dec_f(g_enc[b * 1024 + i]) + b3[i], 0.f);
    __syncthreads();

    for (int o = t; o < 512; o += 256) {
        const float4* wr = (const float4*)(fw1 + (size_t)o * 1024);
        const float4* gv = (const float4*)g;
        float acc = fb1[o];
        for (int i = 0; i < 256; i++) {
            float4 a = wr[i], c = gv[i];
            acc = fmaf(a.x, c.x, acc); acc = fmaf(a.y, c.y, acc);
            acc = fmaf(a.z, c.z, acc); acc = fmaf(a.w, c.w, acc);
        }
        f1[o] = fmaxf(acc, 0.f);
    }
    __syncthreads();
    {
        const int o = t;
        const float4* wr = (const float4*)(fw2 + (size_t)o * 512);
        const float4* fv = (const float4*)f1;
        float acc = fb2[o];
        for (int i = 0; i < 128; i++) {
            float4 a = wr[i], c = fv[i];
            acc = fmaf(a.x, c.x, acc); acc = fmaf(a.y, c.y, acc);
            acc = fmaf(a.z, c.z, acc); acc = fmaf(a.w, c.w, acc);
        }
        f2[o] = fmaxf(acc, 0.f);
    }
    __syncthreads();
    if (t < 9) {
        const float4* wr = (const float4*)(fw3 + (size_t)t * 256);
        const float4* fv = (const float4*)f2;
        float acc = fb3[t];
        for (int i = 0; i < 64; i++) {
            float4 a = wr[i], c = fv[i];
            acc = fmaf(a.x, c.x, acc); acc = fmaf(a.y, c.y, acc);
            acc = fmaf(a.z, c.z, acc); acc = fmaf(a.w, c.w, acc);
        }
        if (t == 0 || t == 4 || t == 8) acc += 1.f;
        tmat[b * 9 + t] = acc;
    }
}

// ---------------------------------------------------------------------------
// K4: out[b][d][n] = sum_c x[b][c][n] * t[b][c][d].  grid 256 x 256.
// ---------------------------------------------------------------------------
__global__ __launch_bounds__(256) void out_kernel(
    const float* __restrict__ x, const float* __restrict__ tmat,
    float* __restrict__ out)
{
    const int gid = blockIdx.x * 256 + threadIdx.x;
    const int b = gid >> 12, n = gid & 4095;
    const float* T = tmat + b * 9;
    const float x0 = x[b * 12288 + n];
    const float x1 = x[b * 12288 + 4096 + n];
    const float x2 = x[b * 12288 + 8192 + n];
    #pragma unroll
    for (int d = 0; d < 3; d++)
        out[b * 12288 + d * 4096 + n] =
            fmaf(x2, T[6 + d], fmaf(x1, T[3 + d], x0 * T[d]));
}

extern "C" void kernel_launch(void* const* d_in, const int* in_sizes, int n_in,
                              void* d_out, int out_size, void* d_ws, size_t ws_size,
                              hipStream_t stream) {
    const float* x   = (const float*)d_in[0];
    const float* w1  = (const float*)d_in[1];
    const float* b1  = (const float*)d_in[2];
    const float* w2  = (const float*)d_in[3];
    const float* b2  = (const float*)d_in[4];
    const float* w3  = (const float*)d_in[5];
    const float* b3  = (const float*)d_in[6];
    const float* fw1 = (const float*)d_in[7];
    const float* fb1 = (const float*)d_in[8];
    const float* fw2 = (const float*)d_in[9];
    const float* fb2 = (const float*)d_in[10];
    const float* fw3 = (const float*)d_in[11];
    const float* fb3 = (const float*)d_in[12];
    float* out = (float*)d_out;

    char* ws = (char*)d_ws;
    unsigned short* idxb = (unsigned short*)ws;
    unsigned* g_enc = (unsigned*)(ws + 4194304);
    unsigned char* w3f8 = (unsigned char*)(ws + 4259840);
    bf16_t* w2sw = (bf16_t*)(ws + 4390912);
    float* tmat  = (float*)(ws + 4407296);

    knn_kernel<<<1024, 512, 0, stream>>>(x, w3, w2, idxb, g_enc, w3f8, w2sw);
    mlp_kernel<<<8192, 256, 0, stream>>>(x, idxb, w1, b1, b2, w2sw, w3f8, g_enc);
    head_kernel<<<16, 256, 0, stream>>>(g_enc, b3, fw1, fb1, fw2, fb2, fw3, fb3, tmat);
    out_kernel<<<256, 256, 0, stream>>>(x, tmat, out);
}

// Round 13
// 613.845 us; speedup vs baseline: 1.3233x; 1.0964x over previous
//
#include <hip/hip_runtime.h>
#include <hip/hip_fp8.h>

typedef __bf16 bf16_t;
typedef __bf16 bf16x8 __attribute__((ext_vector_type(8)));
typedef float floatx16 __attribute__((ext_vector_type(16)));
typedef int intx8 __attribute__((ext_vector_type(8)));
typedef unsigned long long u64;

#define B_ 16
#define N_ 4096
#define K_ 32

// ws layout (bytes):
//   idx   u16 [16][4096][32]         @ 0        (4194304)
//   g_enc u32 [16][1024]             @ 4194304  (65536)
//   w3f8  fp8 frag-major [131072]    @ 4259840  (131072)   (= w3 * 16)
//   w2sw  bf16 frag-major [8192]     @ 4390912  (16384)
//   tmat  f32 [16][9]                @ 4407296  (576)

__device__ __forceinline__ unsigned enc_f(float f) {
    unsigned u = __float_as_uint(f);
    return (u & 0x80000000u) ? ~u : (u | 0x80000000u);
}
__device__ __forceinline__ float dec_f(unsigned e) {
    return __uint_as_float((e & 0x80000000u) ? (e & 0x7fffffffu) : ~e);
}

// ---------------------------------------------------------------------------
// K1: kNN top-32.  16 threads/query x 256 candidates, register top-8
// (packed (dist+1)bits[31:12]|idx[11:0], unconditional med3-chain insert;
// total insert work scales with L only -> L=8 is 25% cheaper than L=12;
// P(chunk holds >8 of a query's true top-32) ~ 1e-4).
// Two-level 4-way tournament merges (128 threads, then 32).
// grid 2048 x 512 (block = 32 queries).
// Side jobs: zero g_enc, build fp8 frag-major w3f8 (x16) + bf16 w2sw.
// ---------------------------------------------------------------------------
__global__ __launch_bounds__(512, 4) void knn_kernel(
    const float* __restrict__ x, const float* __restrict__ w3,
    const float* __restrict__ w2, unsigned short* __restrict__ idxb,
    unsigned* __restrict__ g_enc, unsigned char* __restrict__ w3f8,
    bf16_t* __restrict__ w2sw)
{
    __shared__ __align__(16) float4 cand[16 * 257];   // 65792 B (pad/256: 2-way banks)
    unsigned* lists = (unsigned*)cand;                // 512*9 u32 (reused after scan)
    unsigned* m1 = ((unsigned*)cand) + 8192;          // 32q*4*32 u32 @ 32 KB
    const int tid = threadIdx.x;
    const int bid = blockIdx.x;  // 2048 blocks

    // side jobs.  w3f8 byte o: jj=o&7, half=(o>>3)&1, l=(o>>4)&63,
    // kp=(o>>10)&3, cb=o>>12; ks=kp*2+half, lm=l&31, hi=l>>5;
    // value = fp8(16 * w3[cb*32+lm][ks*16+hi*8+jj]).
    {
        const int g = bid * 512 + tid;
        if (g < 131072) {
            const int jj = g & 7, half = (g >> 3) & 1, lI = (g >> 4) & 63;
            const int kp = (g >> 10) & 3, cb = g >> 12;
            const int ks = kp * 2 + half, lmI = lI & 31, hiI = lI >> 5;
            __hip_fp8_e4m3 t(16.0f * w3[(cb * 32 + lmI) * 128 + ks * 16 + hiI * 8 + jj]);
            w3f8[g] = t.__x;
        } else if (g < 139264) {
            const int o = g - 131072;
            const int f = o >> 9, r = o & 511, lI = r >> 3, jj = r & 7;
            const int ks = f & 3, nb = f >> 2, lmI = lI & 31, hiI = lI >> 5;
            w2sw[o] = (bf16_t)w2[(nb * 32 + lmI) * 64 + ks * 16 + hiI * 8 + jj];
        } else if (g < 155648) {
            g_enc[g - 139264] = 0u;
        }
    }

    const int b  = bid >> 7;                    // 128 blocks per batch
    const int q  = tid >> 4;                    // local query 0..31
    const int n  = (bid & 127) * 32 + q;        // global query index
    const int t  = tid & 15;                    // candidate chunk
    const float* xb = x + b * 3 * N_;

    for (int j = tid; j < N_; j += 512) {
        float cx = xb[j], cy = xb[N_ + j], cz = xb[2 * N_ + j];
        cand[j + (j >> 8)] = make_float4(-2.f * cx, -2.f * cy, -2.f * cz,
                                         fmaf(cx, cx, fmaf(cy, cy, cz * cz)));
    }
    __syncthreads();

    const float xi0 = xb[n], xi1 = xb[N_ + n], xi2 = xb[2 * N_ + n];
    // +1.0 bias keeps d' strictly positive (self-point: 1-eps) -> no clamp,
    // monotone, self stays rank-1 with index tiebreak (matches stable top_k)
    const float xisq1 = fmaf(xi0, xi0, fmaf(xi1, xi1, xi2 * xi2)) + 1.0f;

    unsigned r[8];
    #pragma unroll
    for (int s = 0; s < 8; s++) r[s] = 0x7F7FFFFFu;   // FLT_MAX sentinel

    const int j0 = t * 256;
    const int pb = t * 257;
    #pragma unroll 8
    for (int jj = 0; jj < 256; jj++) {
        const float4 c = cand[pb + jj];
        const float d = fmaf(c.z, xi2, fmaf(c.y, xi1, fmaf(c.x, xi0, c.w)));
        const unsigned key =
            (__float_as_uint(d + xisq1) & 0xFFFFF000u) | (unsigned)(j0 + jj);
        #pragma unroll
        for (int s = 7; s >= 1; s--) {
            const unsigned hv = r[s - 1] > key ? r[s - 1] : key;
            r[s] = r[s] < hv ? r[s] : hv;           // med3
        }
        r[0] = r[0] < key ? r[0] : key;
    }
    __syncthreads();   // cand reads done; reuse LDS

    #pragma unroll
    for (int k = 0; k < 8; k++) lists[tid * 9 + k] = r[k];   // stride 9: 2-way banks
    __syncthreads();

    // level 1: 4 threads/query, each merges 4 sorted-8 lists -> sorted-32
    if (tid < 128) {
        const int q1 = tid >> 2, gi = tid & 3;
        const int base = (q1 * 16 + gi * 4) * 9;
        unsigned h0 = lists[base], h1 = lists[base + 9];
        unsigned h2 = lists[base + 18], h3 = lists[base + 27];
        int p0 = 0, p1 = 0, p2 = 0, p3 = 0;
        unsigned* outp = m1 + (q1 * 4 + gi) * 32;
        #pragma unroll 1
        for (int k = 0; k < 32; k++) {
            const unsigned m01 = h0 < h1 ? h0 : h1;
            const unsigned m23 = h2 < h3 ? h2 : h3;
            const unsigned v = m01 < m23 ? m01 : m23;
            outp[k] = v;
            if (m01 < m23) {
                if (h1 < h0) { p1++; h1 = p1 < 8 ? lists[base + 9 + p1] : 0xFFFFFFFFu; }
                else         { p0++; h0 = p0 < 8 ? lists[base + p0]     : 0xFFFFFFFFu; }
            } else {
                if (h3 < h2) { p3++; h3 = p3 < 8 ? lists[base + 27 + p3] : 0xFFFFFFFFu; }
                else         { p2++; h2 = p2 < 8 ? lists[base + 18 + p2] : 0xFFFFFFFFu; }
            }
        }
    }
    __syncthreads();

    // level 2: 1 thread/query merges 4 sorted-32 lists, emits top-32 indices
    if (tid < 32) {
        const unsigned* g0 = m1 + tid * 128;
        unsigned h0 = g0[0], h1 = g0[32], h2 = g0[64], h3 = g0[96];
        int p0 = 0, p1 = 0, p2 = 0, p3 = 0;
        const int nq = (bid & 127) * 32 + tid;
        unsigned short* op = idxb + ((size_t)(b * N_ + nq)) * K_;
        #pragma unroll 1
        for (int k = 0; k < K_; k++) {
            const unsigned m01 = h0 < h1 ? h0 : h1;
            const unsigned m23 = h2 < h3 ? h2 : h3;
            const unsigned v = m01 < m23 ? m01 : m23;
            op[k] = (unsigned short)(v & 0xFFFu);
            if (m01 < m23) {
                if (h1 < h0) { p1++; h1 = p1 < 32 ? g0[32 + p1] : 0xFFFFFFFFu; }
                else         { p0++; h0 = p0 < 32 ? g0[p0]      : 0xFFFFFFFFu; }
            } else {
                if (h3 < h2) { p3++; h3 = p3 < 32 ? g0[96 + p3] : 0xFFFFFFFFu; }
                else         { p2++; h2 = p2 < 32 ? g0[64 + p2] : 0xFFFFFFFFu; }
            }
        }
    }
}

// ---------------------------------------------------------------------------
// K2: fused edge MLP.  Identical to r12 (channel-split wave pairs, fp8 data,
// K=64 mfma_scale, uint4 B prefetch) EXCEPT launch_bounds (256,3): unified
// reg need ~156 (92 VGPR + 64 AGPR) fits the 170/wave budget at 3 blocks/CU
// -> 50% more resident waves to feed the matrix pipe during VALU stretches.
// Spill tripwire: WRITE_SIZE (baseline 32768 KB).
// ---------------------------------------------------------------------------
__global__ __launch_bounds__(256, 3) void mlp_kernel(
    const float* __restrict__ x, const unsigned short* __restrict__ idxb,
    const float* __restrict__ w1, const float* __restrict__ b1,
    const float* __restrict__ b2,
    const bf16_t* __restrict__ w2sw, const unsigned char* __restrict__ w3f8,
    unsigned* __restrict__ g_enc)
{
    __shared__ __align__(16) unsigned char h2l[256 * 128];  // 32768 B, fp8, swizzled
    __shared__ unsigned gl[1024];                           // 4096 B
    __shared__ __align__(16) float4 w1l[64];                // 1024 B

    const int tid = threadIdx.x;
    const int b   = blockIdx.x >> 9;          // 512 blocks per batch
    const int p0  = (blockIdx.x & 511) * 8;   // first point
    const float* xb = x + b * 3 * N_;

    const int wv = tid >> 6;
    const int l  = tid & 63;
    const int lm = l & 31;
    const int hi = l >> 5;

    for (int i = tid; i < 1024; i += 256) gl[i] = 0u;
    if (tid < 64)
        w1l[tid] = make_float4(w1[tid * 3], w1[tid * 3 + 1], w1[tid * 3 + 2], b1[tid]);
    __syncthreads();

    // ---- layer 1 (VALU) -> A1 frags (bf16) ----
    bf16x8 a1[2][4];   // [mt][ks]; A[m=lm][k=ks*16+hi*8+jj]
    float d0[2], d1[2], d2[2];
    #pragma unroll
    for (int mt = 0; mt < 2; mt++) {
        const int pp = p0 + wv * 2 + mt;                 // wave-uniform
        const int j  = idxb[((size_t)(b * N_ + pp)) * K_ + lm];
        d0[mt] = xb[j]          - xb[pp];
        d1[mt] = xb[N_ + j]     - xb[N_ + pp];
        d2[mt] = xb[2 * N_ + j] - xb[2 * N_ + pp];
    }
    #pragma unroll
    for (int ks = 0; ks < 4; ks++)
        #pragma unroll
        for (int jj = 0; jj < 8; jj++) {
            const float4 w = w1l[ks * 16 + hi * 8 + jj];
            #pragma unroll
            for (int mt = 0; mt < 2; mt++)
                a1[mt][ks][jj] = (bf16_t)fmaxf(
                    fmaf(w.z, d2[mt], fmaf(w.y, d1[mt], fmaf(w.x, d0[mt], w.w))), 0.f);
        }

    // ---- layer 2 (MFMA 32x32x16 bf16), 2x2 (np,nt) passes; epilogue
    //      quantizes h2*256 to fp8 into swizzled LDS (8-byte granules) ----
    #pragma unroll
    for (int np = 0; np < 2; np++)
        #pragma unroll
        for (int nt = 0; nt < 2; nt++) {
            floatx16 acc2[2];
            acc2[0] = (floatx16)0.f; acc2[1] = (floatx16)0.f;
            #pragma unroll
            for (int ks = 0; ks < 4; ks++) {
                const bf16x8 bw2 = *(const bf16x8*)&w2sw[(((np * 2 + nt) * 4 + ks) * 64 + l) * 8];
                acc2[0] = __builtin_amdgcn_mfma_f32_32x32x16_bf16(a1[0][ks], bw2, acc2[0], 0, 0, 0);
                acc2[1] = __builtin_amdgcn_mfma_f32_32x32x16_bf16(a1[1][ks], bw2, acc2[1], 0, 0, 0);
            }
            const int col = np * 64 + nt * 32 + lm;
            const float bias = b2[col];
            const int gcol = col >> 3, cb7 = col & 7;
            #pragma unroll
            for (int mt = 0; mt < 2; mt++)
                #pragma unroll
                for (int reg = 0; reg < 16; reg++) {
                    const int row = wv * 64 + mt * 32 + (reg & 3) + 8 * (reg >> 2) + 4 * hi;
                    __hip_fp8_e4m3 t(fmaxf(acc2[mt][reg] + bias, 0.f) * 256.0f);
                    h2l[row * 128 + ((gcol ^ (row & 15)) << 3) + cb7] = t.__x;
                }
        }
    __syncthreads();   // h2l complete — cross-wave reads follow

    // ---- A3 frags packed for K=64 scaled MFMA: intx8 = 4 ks-frags ----
    const int mh  = wv & 1;          // m-half: edges [mh*128, mh*128+128)
    const int cb0 = (wv >> 1) * 16;  // chunk range: [cb0, cb0+16)
    intx8 a3v[4][2];   // [mt][kq]; components 2*ksq..2*ksq+1 = frag ks=kq*4+ksq
    #pragma unroll
    for (int mt = 0; mt < 4; mt++)
        #pragma unroll
        for (int kq = 0; kq < 2; kq++)
            #pragma unroll
            for (int ksq = 0; ksq < 4; ksq++) {
                const int ks = kq * 4 + ksq;
                const int R = mh * 128 + mt * 32 + lm;
                const int g = ks * 2 + hi;
                const u64 v = *(const u64*)&h2l[R * 128 + ((g ^ (R & 15)) << 3)];
                a3v[mt][kq][2 * ksq]     = (int)(unsigned)(v & 0xFFFFFFFFull);
                a3v[mt][kq][2 * ksq + 1] = (int)(unsigned)(v >> 32);
            }

    // ---- layer 3: 16 chunks of 32 channels per wave; scaled fp8 MFMA
    //      (K=64, scales=1.0), uint4 B prefetch double-buffered, NO barriers ----
    const uint4* w3v = (const uint4*)w3f8;   // 16 B = ks pair (kp)
    intx8 bwA[2], bwB[2];
    #pragma unroll
    for (int kp = 0; kp < 4; kp++) {
        const uint4 v = w3v[(cb0 * 4 + kp) * 64 + l];
        bwA[kp >> 1][(kp & 1) * 4 + 0] = (int)v.x;
        bwA[kp >> 1][(kp & 1) * 4 + 1] = (int)v.y;
        bwA[kp >> 1][(kp & 1) * 4 + 2] = (int)v.z;
        bwA[kp >> 1][(kp & 1) * 4 + 3] = (int)v.w;
    }

    #pragma unroll 1
    for (int cc = 0; cc < 8; cc++) {
        #pragma unroll
        for (int half = 0; half < 2; half++) {
            const int ci = cc * 2 + half;       // 0..15
            const int cb = cb0 + ci;
            intx8* cur = half ? bwB : bwA;
            intx8* nxt = half ? bwA : bwB;
            if (ci < 15) {
                #pragma unroll
                for (int kp = 0; kp < 4; kp++) {
                    const uint4 v = w3v[((cb + 1) * 4 + kp) * 64 + l];
                    nxt[kp >> 1][(kp & 1) * 4 + 0] = (int)v.x;
                    nxt[kp >> 1][(kp & 1) * 4 + 1] = (int)v.y;
                    nxt[kp >> 1][(kp & 1) * 4 + 2] = (int)v.z;
                    nxt[kp >> 1][(kp & 1) * 4 + 3] = (int)v.w;
                }
            }
            floatx16 acc3[4];
            acc3[0] = (floatx16)0.f; acc3[1] = (floatx16)0.f;
            acc3[2] = (floatx16)0.f; acc3[3] = (floatx16)0.f;
            #pragma unroll
            for (int kq = 0; kq < 2; kq++)
                #pragma unroll
                for (int mt = 0; mt < 4; mt++)
                    acc3[mt] = __builtin_amdgcn_mfma_scale_f32_32x32x64_f8f6f4(
                        a3v[mt][kq], cur[kq], acc3[mt],
                        0, 0,                      // cbsz=fp8, blgp=fp8
                        0, 0x7F7F7F7F,             // scale A = 1.0 (E8M0 127)
                        0, 0x7F7F7F7F);            // scale B = 1.0
            // depth-6 parallel max tree over 64 values, undo 256*16 scaling
            float t16[16];
            #pragma unroll
            for (int i = 0; i < 16; i++)
                t16[i] = fmaxf(fmaxf(acc3[0][i], acc3[1][i]),
                               fmaxf(acc3[2][i], acc3[3][i]));
            float t8[8];
            #pragma unroll
            for (int i = 0; i < 8; i++) t8[i] = fmaxf(t16[i], t16[i + 8]);
            float t4[4];
            #pragma unroll
            for (int i = 0; i < 4; i++) t4[i] = fmaxf(t8[i], t8[i + 4]);
            float m = fmaxf(fmaxf(t4[0], t4[1]), fmaxf(t4[2], t4[3]));
            m = fmaxf(m, __shfl_xor(m, 32)) * 2.44140625e-4f;   // 1/4096
            if (hi == 0) atomicMax(&gl[cb * 32 + lm], enc_f(m));
        }
    }

    __syncthreads();
    for (int i = tid; i < 1024; i += 256)
        atomicMax(&g_enc[b * 1024 + i], gl[i]);
}

// ---------------------------------------------------------------------------
// K3: FC head per batch. grid 16 x 256.
// ---------------------------------------------------------------------------
__global__ __launch_bounds__(256) void head_kernel(
    const unsigned* __restrict__ g_enc, const float* __restrict__ b3,
    const float* __restrict__ fw1, const float* __restrict__ fb1,
    const float* __restrict__ fw2, const float* __restrict__ fb2,
    const float* __restrict__ fw3, const float* __restrict__ fb3,
    float* __restrict__ tmat)
{
    __shared__ __align__(16) float g[1024];
    __shared__ __align__(16) float f1[512];
    __shared__ __align__(16) float f2[256];
    const int t = threadIdx.x, b = blockIdx.x;

    for (int i = t; i < 1024; i += 256)
        g[i] = fmaxf(dec_f(g_enc[b * 1024 + i]) + b3[i], 0.f);
    __syncthreads();

    for (int o = t; o < 512; o += 256) {
        const float4* wr = (const float4*)(fw1 + (size_t)o * 1024);
        const float4* gv = (const float4*)g;
        float acc = fb1[o];
        for (int i = 0; i < 256; i++) {
            float4 a = wr[i], c = gv[i];
            acc = fmaf(a.x, c.x, acc); acc = fmaf(a.y, c.y, acc);
            acc = fmaf(a.z, c.z, acc); acc = fmaf(a.w, c.w, acc);
        }
        f1[o] = fmaxf(acc, 0.f);
    }
    __syncthreads();
    {
        const int o = t;
        const float4* wr = (const float4*)(fw2 + (size_t)o * 512);
        const float4* fv = (const float4*)f1;
        float acc = fb2[o];
        for (int i = 0; i < 128; i++) {
            float4 a = wr[i], c = fv[i];
            acc = fmaf(a.x, c.x, acc); acc = fmaf(a.y, c.y, acc);
            acc = fmaf(a.z, c.z, acc); acc = fmaf(a.w, c.w, acc);
        }
        f2[o] = fmaxf(acc, 0.f);
    }
    __syncthreads();
    if (t < 9) {
        const float4* wr = (const float4*)(fw3 + (size_t)t * 256);
        const float4* fv = (const float4*)f2;
        float acc = fb3[t];
        for (int i = 0; i < 64; i++) {
            float4 a = wr[i], c = fv[i];
            acc = fmaf(a.x, c.x, acc); acc = fmaf(a.y, c.y, acc);
            acc = fmaf(a.z, c.z, acc); acc = fmaf(a.w, c.w, acc);
        }
        if (t == 0 || t == 4 || t == 8) acc += 1.f;
        tmat[b * 9 + t] = acc;
    }
}

// ---------------------------------------------------------------------------
// K4: out[b][d][n] = sum_c x[b][c][n] * t[b][c][d].  grid 256 x 256.
// ---------------------------------------------------------------------------
__global__ __launch_bounds__(256) void out_kernel(
    const float* __restrict__ x, const float* __restrict__ tmat,
    float* __restrict__ out)
{
    const int gid = blockIdx.x * 256 + threadIdx.x;
    const int b = gid >> 12, n = gid & 4095;
    const float* T = tmat + b * 9;
    const float x0 = x[b * 12288 + n];
    const float x1 = x[b * 12288 + 4096 + n];
    const float x2 = x[b * 12288 + 8192 + n];
    #pragma unroll
    for (int d = 0; d < 3; d++)
        out[b * 12288 + d * 4096 + n] =
            fmaf(x2, T[6 + d], fmaf(x1, T[3 + d], x0 * T[d]));
}

extern "C" void kernel_launch(void* const* d_in, const int* in_sizes, int n_in,
                              void* d_out, int out_size, void* d_ws, size_t ws_size,
                              hipStream_t stream) {
    const float* x   = (const float*)d_in[0];
    const float* w1  = (const float*)d_in[1];
    const float* b1  = (const float*)d_in[2];
    const float* w2  = (const float*)d_in[3];
    const float* b2  = (const float*)d_in[4];
    const float* w3  = (const float*)d_in[5];
    const float* b3  = (const float*)d_in[6];
    const float* fw1 = (const float*)d_in[7];
    const float* fb1 = (const float*)d_in[8];
    const float* fw2 = (const float*)d_in[9];
    const float* fb2 = (const float*)d_in[10];
    const float* fw3 = (const float*)d_in[11];
    const float* fb3 = (const float*)d_in[12];
    float* out = (float*)d_out;

    char* ws = (char*)d_ws;
    unsigned short* idxb = (unsigned short*)ws;
    unsigned* g_enc = (unsigned*)(ws + 4194304);
    unsigned char* w3f8 = (unsigned char*)(ws + 4259840);
    bf16_t* w2sw = (bf16_t*)(ws + 4390912);
    float* tmat  = (float*)(ws + 4407296);

    knn_kernel<<<2048, 512, 0, stream>>>(x, w3, w2, idxb, g_enc, w3f8, w2sw);
    mlp_kernel<<<8192, 256, 0, stream>>>(x, idxb, w1, b1, b2, w2sw, w3f8, g_enc);
    head_kernel<<<16, 256, 0, stream>>>(g_enc, b3, fw1, fb1, fw2, fb2, fw3, fb3, tmat);
    out_kernel<<<256, 256, 0, stream>>>(x, tmat, out);
}

// Round 14
// 579.625 us; speedup vs baseline: 1.4015x; 1.0590x over previous
//
#include <hip/hip_runtime.h>
#include <hip/hip_fp8.h>

typedef __bf16 bf16_t;
typedef __bf16 bf16x8 __attribute__((ext_vector_type(8)));
typedef float floatx16 __attribute__((ext_vector_type(16)));
typedef int intx8 __attribute__((ext_vector_type(8)));
typedef unsigned long long u64;

#define B_ 16
#define N_ 4096
#define K_ 32

// ws layout (bytes):
//   idx   u16 [16][4096][32]         @ 0        (4194304)
//   g_enc u32 [16][1024]             @ 4194304  (65536)
//   w3f8  fp8 frag-major [131072]    @ 4259840  (131072)   (= w3 * 16)
//   w2sw  bf16 frag-major [8192]     @ 4390912  (16384)
//   tmat  f32 [16][9]                @ 4407296  (576)

__device__ __forceinline__ unsigned enc_f(float f) {
    unsigned u = __float_as_uint(f);
    return (u & 0x80000000u) ? ~u : (u | 0x80000000u);
}
__device__ __forceinline__ float dec_f(unsigned e) {
    return __uint_as_float((e & 0x80000000u) ? (e & 0x7fffffffu) : ~e);
}

// ---------------------------------------------------------------------------
// K1: kNN top-32 (r13 core, unchanged).  16 threads/query x 256 candidates,
// register top-8, unconditional med3-chain insert, two-level 4-way merges.
// grid 2048 x 512.  Side jobs: zero g_enc, build w3f8 + w2sw.
// NEW w3f8 layout (matches mlp's transposed layer-2 k-map): byte
// o = ((cb*4 + mt2)*64 + l)*16 + q  ->  fp8(16 * w3[cb*32 + (l&31)]
//     [mt2*32 + (q&3) + 8*(q>>2) + 4*(l>>5)]).
// Each (cb,mt2) slice is 1 KB contiguous = one coalesced dwordx4 per wave.
// ---------------------------------------------------------------------------
__global__ __launch_bounds__(512, 4) void knn_kernel(
    const float* __restrict__ x, const float* __restrict__ w3,
    const float* __restrict__ w2, unsigned short* __restrict__ idxb,
    unsigned* __restrict__ g_enc, unsigned char* __restrict__ w3f8,
    bf16_t* __restrict__ w2sw)
{
    __shared__ __align__(16) float4 cand[16 * 257];   // 65792 B
    unsigned* lists = (unsigned*)cand;                // reused after scan
    unsigned* m1 = ((unsigned*)cand) + 8192;          // merge scratch @ 32 KB
    const int tid = threadIdx.x;
    const int bid = blockIdx.x;  // 2048 blocks

    {
        const int g = bid * 512 + tid;
        if (g < 131072) {
            const int q = g & 15, lI = (g >> 4) & 63, mt2 = (g >> 10) & 3, cb = g >> 12;
            const int lmI = lI & 31, hiI = lI >> 5;
            const int ch = mt2 * 32 + (q & 3) + 8 * (q >> 2) + 4 * hiI;
            __hip_fp8_e4m3 t(16.0f * w3[(cb * 32 + lmI) * 128 + ch]);
            w3f8[g] = t.__x;
        } else if (g < 139264) {
            const int o = g - 131072;
            const int f = o >> 9, r = o & 511, lI = r >> 3, jj = r & 7;
            const int ks = f & 3, nb = f >> 2, lmI = lI & 31, hiI = lI >> 5;
            w2sw[o] = (bf16_t)w2[(nb * 32 + lmI) * 64 + ks * 16 + hiI * 8 + jj];
        } else if (g < 155648) {
            g_enc[g - 139264] = 0u;
        }
    }

    const int b  = bid >> 7;                    // 128 blocks per batch
    const int q  = tid >> 4;                    // local query 0..31
    const int n  = (bid & 127) * 32 + q;        // global query index
    const int t  = tid & 15;                    // candidate chunk
    const float* xb = x + b * 3 * N_;

    for (int j = tid; j < N_; j += 512) {
        float cx = xb[j], cy = xb[N_ + j], cz = xb[2 * N_ + j];
        cand[j + (j >> 8)] = make_float4(-2.f * cx, -2.f * cy, -2.f * cz,
                                         fmaf(cx, cx, fmaf(cy, cy, cz * cz)));
    }
    __syncthreads();

    const float xi0 = xb[n], xi1 = xb[N_ + n], xi2 = xb[2 * N_ + n];
    const float xisq1 = fmaf(xi0, xi0, fmaf(xi1, xi1, xi2 * xi2)) + 1.0f;

    unsigned r[8];
    #pragma unroll
    for (int s = 0; s < 8; s++) r[s] = 0x7F7FFFFFu;   // FLT_MAX sentinel

    const int j0 = t * 256;
    const int pb = t * 257;
    #pragma unroll 8
    for (int jj = 0; jj < 256; jj++) {
        const float4 c = cand[pb + jj];
        const float d = fmaf(c.z, xi2, fmaf(c.y, xi1, fmaf(c.x, xi0, c.w)));
        const unsigned key =
            (__float_as_uint(d + xisq1) & 0xFFFFF000u) | (unsigned)(j0 + jj);
        #pragma unroll
        for (int s = 7; s >= 1; s--) {
            const unsigned hv = r[s - 1] > key ? r[s - 1] : key;
            r[s] = r[s] < hv ? r[s] : hv;           // med3
        }
        r[0] = r[0] < key ? r[0] : key;
    }
    __syncthreads();

    #pragma unroll
    for (int k = 0; k < 8; k++) lists[tid * 9 + k] = r[k];
    __syncthreads();

    if (tid < 128) {
        const int q1 = tid >> 2, gi = tid & 3;
        const int base = (q1 * 16 + gi * 4) * 9;
        unsigned h0 = lists[base], h1 = lists[base + 9];
        unsigned h2 = lists[base + 18], h3 = lists[base + 27];
        int p0 = 0, p1 = 0, p2 = 0, p3 = 0;
        unsigned* outp = m1 + (q1 * 4 + gi) * 32;
        #pragma unroll 1
        for (int k = 0; k < 32; k++) {
            const unsigned m01 = h0 < h1 ? h0 : h1;
            const unsigned m23 = h2 < h3 ? h2 : h3;
            const unsigned v = m01 < m23 ? m01 : m23;
            outp[k] = v;
            if (m01 < m23) {
                if (h1 < h0) { p1++; h1 = p1 < 8 ? lists[base + 9 + p1] : 0xFFFFFFFFu; }
                else         { p0++; h0 = p0 < 8 ? lists[base + p0]     : 0xFFFFFFFFu; }
            } else {
                if (h3 < h2) { p3++; h3 = p3 < 8 ? lists[base + 27 + p3] : 0xFFFFFFFFu; }
                else         { p2++; h2 = p2 < 8 ? lists[base + 18 + p2] : 0xFFFFFFFFu; }
            }
        }
    }
    __syncthreads();

    if (tid < 32) {
        const unsigned* g0 = m1 + tid * 128;
        unsigned h0 = g0[0], h1 = g0[32], h2 = g0[64], h3 = g0[96];
        int p0 = 0, p1 = 0, p2 = 0, p3 = 0;
        const int nq = (bid & 127) * 32 + tid;
        unsigned short* op = idxb + ((size_t)(b * N_ + nq)) * K_;
        #pragma unroll 1
        for (int k = 0; k < K_; k++) {
            const unsigned m01 = h0 < h1 ? h0 : h1;
            const unsigned m23 = h2 < h3 ? h2 : h3;
            const unsigned v = m01 < m23 ? m01 : m23;
            op[k] = (unsigned short)(v & 0xFFFu);
            if (m01 < m23) {
                if (h1 < h0) { p1++; h1 = p1 < 32 ? g0[32 + p1] : 0xFFFFFFFFu; }
                else         { p0++; h0 = p0 < 32 ? g0[p0]      : 0xFFFFFFFFu; }
            } else {
                if (h3 < h2) { p3++; h3 = p3 < 32 ? g0[96 + p3] : 0xFFFFFFFFu; }
                else         { p2++; h2 = p2 < 32 ? g0[64 + p2] : 0xFFFFFFFFu; }
            }
        }
    }
}

// ---------------------------------------------------------------------------
// K2: fused edge MLP, TRANSPOSED layer 2 — no h2 LDS round-trip.
// Layer 2 computes h2^T: A = w2 (channels as M), B = h1 (edges as N, built
// directly by layer-1 VALU).  C/D col = edge (lane&31), row = channel with
// channel = mt2*32+(reg&3)+8*(reg>>2)+4*hi — each lane ends up holding
// exactly the 32-channel k-slices its layer-3 A-frag needs, so A3 is a pure
// in-register repack: fused fma(bias,relu,x256) + v_cvt_pk_fp8_f32 pairs.
// Layer 3: all 32 chunks per wave, fp8 MX-scaled K=64 MFMA (scales=1.0),
// uint4 B prefetch double-buffered; w3f8's k-map matches A3's exactly.
// LDS: 5.6 KB (gl + w1l + b2s).  No spill expected at (256,3).
// ---------------------------------------------------------------------------
__global__ __launch_bounds__(256, 3) void mlp_kernel(
    const float* __restrict__ x, const unsigned short* __restrict__ idxb,
    const float* __restrict__ w1, const float* __restrict__ b1,
    const float* __restrict__ b2,
    const bf16_t* __restrict__ w2sw, const unsigned char* __restrict__ w3f8,
    unsigned* __restrict__ g_enc)
{
    __shared__ unsigned gl[1024];                 // 4096 B
    __shared__ __align__(16) float4 w1l[64];      // 1024 B
    __shared__ __align__(16) float b2s[128];      // 512 B  (= 256*b2)

    const int tid = threadIdx.x;
    const int b   = blockIdx.x >> 9;          // 512 blocks per batch
    const int p0  = (blockIdx.x & 511) * 8;   // first point
    const float* xb = x + b * 3 * N_;

    const int wv = tid >> 6;
    const int l  = tid & 63;
    const int lm = l & 31;
    const int hi = l >> 5;

    for (int i = tid; i < 1024; i += 256) gl[i] = 0u;
    if (tid < 64)
        w1l[tid] = make_float4(w1[tid * 3], w1[tid * 3 + 1], w1[tid * 3 + 2], b1[tid]);
    else if (tid < 192)
        b2s[tid - 64] = 256.0f * b2[tid - 64];
    __syncthreads();

    // ---- prefetch layer-3 B chunk 0 (in flight during layers 1+2) ----
    const uint4* w3v = (const uint4*)w3f8;
    intx8 bwA[2], bwB[2];
    #pragma unroll
    for (int mt2 = 0; mt2 < 4; mt2++) {
        const uint4 v = w3v[mt2 * 64 + l];
        bwA[mt2 >> 1][(mt2 & 1) * 4 + 0] = (int)v.x;
        bwA[mt2 >> 1][(mt2 & 1) * 4 + 1] = (int)v.y;
        bwA[mt2 >> 1][(mt2 & 1) * 4 + 2] = (int)v.z;
        bwA[mt2 >> 1][(mt2 & 1) * 4 + 3] = (int)v.w;
    }

    // ---- layer 1 (VALU) -> h1 B-frags (edges as N) ----
    bf16x8 b1h[2][4];   // [nt2][ks]; B[n=lm (edge of point nt2)][k=ks*16+hi*8+jj]
    float d0[2], d1[2], d2[2];
    #pragma unroll
    for (int nt2 = 0; nt2 < 2; nt2++) {
        const int pp = p0 + wv * 2 + nt2;                // wave-uniform point
        const int j  = idxb[((size_t)(b * N_ + pp)) * K_ + lm];
        d0[nt2] = xb[j]          - xb[pp];
        d1[nt2] = xb[N_ + j]     - xb[N_ + pp];
        d2[nt2] = xb[2 * N_ + j] - xb[2 * N_ + pp];
    }
    #pragma unroll
    for (int ks = 0; ks < 4; ks++)
        #pragma unroll
        for (int jj = 0; jj < 8; jj++) {
            const float4 w = w1l[ks * 16 + hi * 8 + jj];
            #pragma unroll
            for (int nt2 = 0; nt2 < 2; nt2++)
                b1h[nt2][ks][jj] = (bf16_t)fmaxf(
                    fmaf(w.z, d2[nt2], fmaf(w.y, d1[nt2], fmaf(w.x, d0[nt2], w.w))), 0.f);
        }

    // ---- layer 2 (MFMA 32x32x16 bf16, transposed) + fused fp8 pack -> a3v ----
    intx8 a3v[2][2];   // [nt2 = edge m-tile][kq]; byte map matches w3f8
    #pragma unroll
    for (int mt2 = 0; mt2 < 4; mt2++) {          // channel tile (M side)
        floatx16 acc0 = (floatx16)0.f, acc1 = (floatx16)0.f;
        #pragma unroll
        for (int ks = 0; ks < 4; ks++) {
            const bf16x8 aw = *(const bf16x8*)&w2sw[((mt2 * 4 + ks) * 64 + l) * 8];
            acc0 = __builtin_amdgcn_mfma_f32_32x32x16_bf16(aw, b1h[0][ks], acc0, 0, 0, 0);
            acc1 = __builtin_amdgcn_mfma_f32_32x32x16_bf16(aw, b1h[1][ks], acc1, 0, 0, 0);
        }
        const int kq = mt2 >> 1, c0 = (mt2 & 1) * 4;
        #pragma unroll
        for (int i2 = 0; i2 < 4; i2++) {
            // channels mt2*32 + 8*i2 + 4*hi + {0..3}  (lane-uniform per hi)
            const float4 bb = *(const float4*)&b2s[mt2 * 32 + i2 * 8 + hi * 4];
            {
                const float v0 = fmaxf(fmaf(acc0[4 * i2 + 0], 256.f, bb.x), 0.f);
                const float v1 = fmaxf(fmaf(acc0[4 * i2 + 1], 256.f, bb.y), 0.f);
                const float v2 = fmaxf(fmaf(acc0[4 * i2 + 2], 256.f, bb.z), 0.f);
                const float v3 = fmaxf(fmaf(acc0[4 * i2 + 3], 256.f, bb.w), 0.f);
                int w = __builtin_amdgcn_cvt_pk_fp8_f32(v0, v1, 0, false);
                w = __builtin_amdgcn_cvt_pk_fp8_f32(v2, v3, w, true);
                a3v[0][kq][c0 + i2] = w;
            }
            {
                const float v0 = fmaxf(fmaf(acc1[4 * i2 + 0], 256.f, bb.x), 0.f);
                const float v1 = fmaxf(fmaf(acc1[4 * i2 + 1], 256.f, bb.y), 0.f);
                const float v2 = fmaxf(fmaf(acc1[4 * i2 + 2], 256.f, bb.z), 0.f);
                const float v3 = fmaxf(fmaf(acc1[4 * i2 + 3], 256.f, bb.w), 0.f);
                int w = __builtin_amdgcn_cvt_pk_fp8_f32(v0, v1, 0, false);
                w = __builtin_amdgcn_cvt_pk_fp8_f32(v2, v3, w, true);
                a3v[1][kq][c0 + i2] = w;
            }
        }
    }

    // ---- layer 3: 32 chunks of 32 out-channels; scaled fp8 MFMA (K=64),
    //      uint4 B prefetch double-buffered, NO barriers ----
    #pragma unroll 1
    for (int cc = 0; cc < 16; cc++) {
        #pragma unroll
        for (int half = 0; half < 2; half++) {
            const int cb = cc * 2 + half;       // 0..31
            intx8* cur = half ? bwB : bwA;
            intx8* nxt = half ? bwA : bwB;
            if (cb < 31) {
                #pragma unroll
                for (int mt2 = 0; mt2 < 4; mt2++) {
                    const uint4 v = w3v[((cb + 1) * 4 + mt2) * 64 + l];
                    nxt[mt2 >> 1][(mt2 & 1) * 4 + 0] = (int)v.x;
                    nxt[mt2 >> 1][(mt2 & 1) * 4 + 1] = (int)v.y;
                    nxt[mt2 >> 1][(mt2 & 1) * 4 + 2] = (int)v.z;
                    nxt[mt2 >> 1][(mt2 & 1) * 4 + 3] = (int)v.w;
                }
            }
            floatx16 acc3[2];
            acc3[0] = (floatx16)0.f; acc3[1] = (floatx16)0.f;
            #pragma unroll
            for (int kq = 0; kq < 2; kq++)
                #pragma unroll
                for (int mt3 = 0; mt3 < 2; mt3++)
                    acc3[mt3] = __builtin_amdgcn_mfma_scale_f32_32x32x64_f8f6f4(
                        a3v[mt3][kq], cur[kq], acc3[mt3],
                        0, 0,                      // cbsz=fp8, blgp=fp8
                        0, 0x7F7F7F7F,             // scale A = 1.0 (E8M0 127)
                        0, 0x7F7F7F7F);            // scale B = 1.0
            // depth-5 tree over 32 values, undo 256*16 scaling
            float t16[16];
            #pragma unroll
            for (int i = 0; i < 16; i++) t16[i] = fmaxf(acc3[0][i], acc3[1][i]);
            float t8[8];
            #pragma unroll
            for (int i = 0; i < 8; i++) t8[i] = fmaxf(t16[i], t16[i + 8]);
            float t4[4];
            #pragma unroll
            for (int i = 0; i < 4; i++) t4[i] = fmaxf(t8[i], t8[i + 4]);
            float m = fmaxf(fmaxf(t4[0], t4[1]), fmaxf(t4[2], t4[3]));
            m = fmaxf(m, __shfl_xor(m, 32)) * 2.44140625e-4f;   // 1/4096
            if (hi == 0) atomicMax(&gl[cb * 32 + lm], enc_f(m));
        }
    }

    __syncthreads();
    for (int i = tid; i < 1024; i += 256)
        atomicMax(&g_enc[b * 1024 + i], gl[i]);
}

// ---------------------------------------------------------------------------
// K3: FC head per batch. grid 16 x 256.
// ---------------------------------------------------------------------------
__global__ __launch_bounds__(256) void head_kernel(
    const unsigned* __restrict__ g_enc, const float* __restrict__ b3,
    const float* __restrict__ fw1, const float* __restrict__ fb1,
    const float* __restrict__ fw2, const float* __restrict__ fb2,
    const float* __restrict__ fw3, const float* __restrict__ fb3,
    float* __restrict__ tmat)
{
    __shared__ __align__(16) float g[1024];
    __shared__ __align__(16) float f1[512];
    __shared__ __align__(16) float f2[256];
    const int t = threadIdx.x, b = blockIdx.x;

    for (int i = t; i < 1024; i += 256)
        g[i] = fmaxf(dec_f(g_enc[b * 1024 + i]) + b3[i], 0.f);
    __syncthreads();

    for (int o = t; o < 512; o += 256) {
        const float4* wr = (const float4*)(fw1 + (size_t)o * 1024);
        const float4* gv = (const float4*)g;
        float acc = fb1[o];
        for (int i = 0; i < 256; i++) {
            float4 a = wr[i], c = gv[i];
            acc = fmaf(a.x, c.x, acc); acc = fmaf(a.y, c.y, acc);
            acc = fmaf(a.z, c.z, acc); acc = fmaf(a.w, c.w, acc);
        }
        f1[o] = fmaxf(acc, 0.f);
    }
    __syncthreads();
    {
        const int o = t;
        const float4* wr = (const float4*)(fw2 + (size_t)o * 512);
        const float4* fv = (const float4*)f1;
        float acc = fb2[o];
        for (int i = 0; i < 128; i++) {
            float4 a = wr[i], c = fv[i];
            acc = fmaf(a.x, c.x, acc); acc = fmaf(a.y, c.y, acc);
            acc = fmaf(a.z, c.z, acc); acc = fmaf(a.w, c.w, acc);
        }
        f2[o] = fmaxf(acc, 0.f);
    }
    __syncthreads();
    if (t < 9) {
        const float4* wr = (const float4*)(fw3 + (size_t)t * 256);
        const float4* fv = (const float4*)f2;
        float acc = fb3[t];
        for (int i = 0; i < 64; i++) {
            float4 a = wr[i], c = fv[i];
            acc = fmaf(a.x, c.x, acc); acc = fmaf(a.y, c.y, acc);
            acc = fmaf(a.z, c.z, acc); acc = fmaf(a.w, c.w, acc);
        }
        if (t == 0 || t == 4 || t == 8) acc += 1.f;
        tmat[b * 9 + t] = acc;
    }
}

// ---------------------------------------------------------------------------
// K4: out[b][d][n] = sum_c x[b][c][n] * t[b][c][d].  grid 256 x 256.
// ---------------------------------------------------------------------------
__global__ __launch_bounds__(256) void out_kernel(
    const float* __restrict__ x, const float* __restrict__ tmat,
    float* __restrict__ out)
{
    const int gid = blockIdx.x * 256 + threadIdx.x;
    const int b = gid >> 12, n = gid & 4095;
    const float* T = tmat + b * 9;
    const float x0 = x[b * 12288 + n];
    const float x1 = x[b * 12288 + 4096 + n];
    const float x2 = x[b * 12288 + 8192 + n];
    #pragma unroll
    for (int d = 0; d < 3; d++)
        out[b * 12288 + d * 4096 + n] =
            fmaf(x2, T[6 + d], fmaf(x1, T[3 + d], x0 * T[d]));
}

extern "C" void kernel_launch(void* const* d_in, const int* in_sizes, int n_in,
                              void* d_out, int out_size, void* d_ws, size_t ws_size,
                              hipStream_t stream) {
    const float* x   = (const float*)d_in[0];
    const float* w1  = (const float*)d_in[1];
    const float* b1  = (const float*)d_in[2];
    const float* w2  = (const float*)d_in[3];
    const float* b2  = (const float*)d_in[4];
    const float* w3  = (const float*)d_in[5];
    const float* b3  = (const float*)d_in[6];
    const float* fw1 = (const float*)d_in[7];
    const float* fb1 = (const float*)d_in[8];
    const float* fw2 = (const float*)d_in[9];
    const float* fb2 = (const float*)d_in[10];
    const float* fw3 = (const float*)d_in[11];
    const float* fb3 = (const float*)d_in[12];
    float* out = (float*)d_out;

    char* ws = (char*)d_ws;
    unsigned short* idxb = (unsigned short*)ws;
    unsigned* g_enc = (unsigned*)(ws + 4194304);
    unsigned char* w3f8 = (unsigned char*)(ws + 4259840);
    bf16_t* w2sw = (bf16_t*)(ws + 4390912);
    float* tmat  = (float*)(ws + 4407296);

    knn_kernel<<<2048, 512, 0, stream>>>(x, w3, w2, idxb, g_enc, w3f8, w2sw);
    mlp_kernel<<<8192, 256, 0, stream>>>(x, idxb, w1, b1, b2, w2sw, w3f8, g_enc);
    head_kernel<<<16, 256, 0, stream>>>(g_enc, b3, fw1, fb1, fw2, fb2, fw3, fb3, tmat);
    out_kernel<<<256, 256, 0, stream>>>(x, tmat, out);
}